// Round 12
// baseline (2942.798 us; speedup 1.0000x reference)
//
#include <hip/hip_runtime.h>
#include <math.h>
#include <stdint.h>

#define NBATCH 32
#define SEQ 197
#define DIM 768
#define NHEAD 12
#define DH 64
#define MDIM 3072
#define NLAYER 12
#define NPATCH 196
#define NOUT 1000
#define MROWS (NBATCH * SEQ)   // 6304
#define SPLITK 2

typedef __bf16 bf16x8 __attribute__((ext_vector_type(8)));
typedef float f32x4 __attribute__((ext_vector_type(4)));

__device__ __forceinline__ unsigned short f2bf(float f) {
    unsigned u = __float_as_uint(f);
    unsigned r = u + 0x7fffu + ((u >> 16) & 1u);
    return (unsigned short)(r >> 16);
}

__device__ __forceinline__ f32x4 mfma16(bf16x8 a, bf16x8 b, f32x4 c) {
    return __builtin_amdgcn_mfma_f32_16x16x32_bf16(a, b, c, 0, 0, 0);
}

// async global->LDS 16B: lds pointer wave-uniform base; HW writes lane l at base + l*16.
__device__ __forceinline__ void gload_lds16(const void* g, const void* lds) {
    __builtin_amdgcn_global_load_lds(
        (const __attribute__((address_space(1))) void*)(uintptr_t)g,
        (__attribute__((address_space(3))) void*)(uint32_t)(uintptr_t)lds,
        16, 0, 0);
}

#define WAIT_VMCNT_6() asm volatile("s_waitcnt vmcnt(6)" ::: "memory")
#define WAIT_VMCNT_4() asm volatile("s_waitcnt vmcnt(4)" ::: "memory")
#define WAIT_VMCNT_0() asm volatile("s_waitcnt vmcnt(0)" ::: "memory")
#define BARRIER_RAW()                      \
    do {                                   \
        asm volatile("" ::: "memory");     \
        __builtin_amdgcn_s_barrier();      \
        asm volatile("" ::: "memory");     \
    } while (0)

// ---------------- fp32 -> bf16 converter (grid-stride) ----------------
__global__ __launch_bounds__(256) void cvt4(const float* __restrict__ src,
                                            unsigned short* __restrict__ dst, int n4) {
    int stride = gridDim.x * 256;
    for (int i = blockIdx.x * 256 + threadIdx.x; i < n4; i += stride) {
        float4 f = *(const float4*)(src + (size_t)i * 4);
        ushort4 o;
        o.x = f2bf(f.x); o.y = f2bf(f.y); o.z = f2bf(f.z); o.w = f2bf(f.w);
        *(ushort4*)(dst + (size_t)i * 4) = o;
    }
}

// gather Wq/Wk/Wv [L][H][e][d] -> wqkvb [L][H][3*64 rows][64] bf16
__global__ __launch_bounds__(256) void cvt_qkvw(const float* __restrict__ Wq,
                                                const float* __restrict__ Wk,
                                                const float* __restrict__ Wv,
                                                unsigned short* __restrict__ dst) {
    const int n = NLAYER * NHEAD * 3 * 64 * 64;
    int stride = gridDim.x * 256;
    for (int i = blockIdx.x * 256 + threadIdx.x; i < n; i += stride) {
        int d = i & 63, e = (i >> 6) & 63;
        int v = i >> 12;
        int t = v % 3, hh = (v / 3) % NHEAD, l = v / (3 * NHEAD);
        const float* src = (t == 0) ? Wq : (t == 1) ? Wk : Wv;
        dst[i] = f2bf(src[(((size_t)(l * NHEAD + hh)) * 64 + e) * 64 + d]);
    }
}

// ---------------- cls + pos init ----------------
__global__ __launch_bounds__(256) void cls_pos_kernel(const float* __restrict__ cls,
                                                      const float* __restrict__ pos,
                                                      float* __restrict__ x) {
    int b = blockIdx.x, tid = threadIdx.x;
#pragma unroll
    for (int i = 0; i < 3; i++) {
        int c = tid + i * 256;
        x[(size_t)b * SEQ * DIM + c] = cls[c] + pos[c];
    }
}

// ---------------- patch-embed GEMM: bf16 MFMA, gathered A, counted-vmcnt dbuf ----------------
__global__ __launch_bounds__(256) void gemm_patch_bf(const unsigned short* __restrict__ imgbf,
                                                     const unsigned short* __restrict__ wpbf,
                                                     const float* __restrict__ bp,
                                                     const float* __restrict__ pos,
                                                     float* __restrict__ x) {
    __shared__ __align__(16) unsigned short As[2][128 * 32];
    __shared__ __align__(16) unsigned short Bs[2][128 * 32];
    const int t = threadIdx.x, l = t & 63, w = t >> 6;
    const int bm = blockIdx.x * 128, bn = blockIdx.y * 128;
    const int wr = w >> 1, wc = w & 1;
    f32x4 acc[4][4] = {};

    const int ra0 = t >> 2, ka0 = (t & 3) * 8;
    const int ra1 = (t + 256) >> 2, ka1 = ((t + 256) & 3) * 8;
    int gm0 = bm + ra0, b0 = gm0 / NPATCH, p0 = gm0 % NPATCH;
    int gm1 = bm + ra1, b1 = gm1 / NPATCH, p1 = gm1 % NPATCH;
    const unsigned short* ib0 =
        imgbf + ((size_t)b0 * 3 * 224 + (size_t)(p0 / 14) * 16) * 224 + (p0 % 14) * 16;
    const unsigned short* ib1 =
        imgbf + ((size_t)b1 * 3 * 224 + (size_t)(p1 / 14) * 16) * 224 + (p1 % 14) * 16;
    const unsigned short* Br0 = wpbf + (size_t)(bn + ra0) * 768 + ka0;
    const unsigned short* Br1 = wpbf + (size_t)(bn + ra1) * 768 + ka1;
    const int lA0 = (0 * 256 + w * 64) * 8, lA1 = (1 * 256 + w * 64) * 8;
    const int lr = l & 15, lk = (l >> 4) * 8;

#define PATCH_STAGE(buf, k0)                                                   \
    {                                                                          \
        int kA0 = (k0) + ka0, kA1 = (k0) + ka1;                                \
        int c0 = kA0 >> 8, i0 = (kA0 >> 4) & 15, j0 = kA0 & 15;                \
        int c1 = kA1 >> 8, i1 = (kA1 >> 4) & 15, j1 = kA1 & 15;                \
        gload_lds16(ib0 + ((size_t)c0 * 224 + i0) * 224 + j0, As[buf] + lA0);  \
        gload_lds16(ib1 + ((size_t)c1 * 224 + i1) * 224 + j1, As[buf] + lA1);  \
        gload_lds16(Br0 + (k0), Bs[buf] + lA0);                                \
        gload_lds16(Br1 + (k0), Bs[buf] + lA1);                                \
    }

    PATCH_STAGE(0, 0);
    int cur = 0;
    for (int k0 = 0; k0 < 768; k0 += 32) {
        if (k0 + 32 < 768) {
            PATCH_STAGE(cur ^ 1, k0 + 32);
            WAIT_VMCNT_4();
        } else {
            WAIT_VMCNT_0();
        }
        BARRIER_RAW();
        bf16x8 a[4], bfr[4];
#pragma unroll
        for (int m = 0; m < 4; m++)
            a[m] = *(const bf16x8*)(As[cur] + (wr * 64 + m * 16 + lr) * 32 + lk);
#pragma unroll
        for (int n = 0; n < 4; n++)
            bfr[n] = *(const bf16x8*)(Bs[cur] + (wc * 64 + n * 16 + lr) * 32 + lk);
#pragma unroll
        for (int m = 0; m < 4; m++)
#pragma unroll
            for (int n = 0; n < 4; n++)
                acc[m][n] = mfma16(a[m], bfr[n], acc[m][n]);
        BARRIER_RAW();
        cur ^= 1;
    }
#undef PATCH_STAGE

#pragma unroll
    for (int m = 0; m < 4; m++) {
#pragma unroll
        for (int r = 0; r < 4; r++) {
            int gm = bm + wr * 64 + m * 16 + (l >> 4) * 4 + r;
            int b2 = gm / NPATCH, p2 = gm % NPATCH;
            size_t orow = (size_t)(b2 * SEQ + 1 + p2) * DIM;
#pragma unroll
            for (int n = 0; n < 4; n++) {
                int gn = bn + wc * 64 + n * 16 + lr;
                x[orow + gn] = acc[m][n][r] + bp[gn] + pos[(size_t)(1 + p2) * DIM + gn];
            }
        }
    }
}

// ---------------- wave-per-row LayerNorm, bf16 h out ----------------
template <int RES, int RED>
__global__ __launch_bounds__(256) void ln_wave(const float* __restrict__ x_in,
                                               const float* __restrict__ addv,
                                               float* __restrict__ x_out,
                                               unsigned short* __restrict__ h_out,
                                               const float* __restrict__ g,
                                               const float* __restrict__ bb,
                                               const float* __restrict__ parts,
                                               const float* __restrict__ badd,
                                               int xmul) {
    int w = threadIdx.x >> 6, l = threadIdx.x & 63;
    size_t row = (size_t)blockIdx.x * 4 + w;
    size_t xrow = row * xmul;
    const float* xr = x_in + xrow * DIM;
    float4 v[3];
    float s = 0.f;
#pragma unroll
    for (int u = 0; u < 3; u++) {
        int c = u * 256 + l * 4;
        v[u] = *(const float4*)(xr + c);
        if (RES) {
            float4 a4 = *(const float4*)(addv + xrow * DIM + c);
            v[u].x += a4.x; v[u].y += a4.y; v[u].z += a4.z; v[u].w += a4.w;
        }
        if (RED) {
            float4 b4 = *(const float4*)(badd + c);
            v[u].x += b4.x; v[u].y += b4.y; v[u].z += b4.z; v[u].w += b4.w;
#pragma unroll
            for (int kc = 0; kc < SPLITK; kc++) {
                float4 p4 = *(const float4*)(parts + ((size_t)kc * MROWS + row) * DIM + c);
                v[u].x += p4.x; v[u].y += p4.y; v[u].z += p4.z; v[u].w += p4.w;
            }
        }
        s += v[u].x + v[u].y + v[u].z + v[u].w;
    }
#pragma unroll
    for (int o = 1; o < 64; o <<= 1) s += __shfl_xor(s, o, 64);
    float mean = s * (1.0f / 768.0f);
    float s2 = 0.f;
#pragma unroll
    for (int u = 0; u < 3; u++) {
        float dx = v[u].x - mean, dy = v[u].y - mean, dz = v[u].z - mean, dw = v[u].w - mean;
        s2 += dx * dx + dy * dy + dz * dz + dw * dw;
    }
#pragma unroll
    for (int o = 1; o < 64; o <<= 1) s2 += __shfl_xor(s2, o, 64);
    float inv = rsqrtf(s2 * (1.0f / 768.0f) + 1e-5f);
#pragma unroll
    for (int u = 0; u < 3; u++) {
        int c = u * 256 + l * 4;
        float4 g4 = *(const float4*)(g + c);
        float4 b4 = *(const float4*)(bb + c);
        ushort4 o;
        o.x = f2bf((v[u].x - mean) * inv * g4.x + b4.x);
        o.y = f2bf((v[u].y - mean) * inv * g4.y + b4.y);
        o.z = f2bf((v[u].z - mean) * inv * g4.z + b4.z);
        o.w = f2bf((v[u].w - mean) * inv * g4.w + b4.w);
        *(ushort4*)(h_out + row * DIM + c) = o;
        if (RES || RED) *(float4*)(x_out + xrow * DIM + c) = v[u];
    }
}

// ================= fused QKV projection + attention =================
#define KS_OFF 0
#define QS_OFF 14400
#define VT_OFF 28800
#define RG_OFF 43648
#define WS_OFF (RG_OFF + 14400)

template <int QTMAX>
__global__ __launch_bounds__(512) void fused_attn(const unsigned short* __restrict__ hbf,
                                                  const unsigned short* __restrict__ wqkv,
                                                  const float* __restrict__ bq,
                                                  const float* __restrict__ bk,
                                                  const float* __restrict__ bv,
                                                  float* __restrict__ o) {
    __shared__ __align__(16) unsigned short lds[73344];
    const int b = blockIdx.x, hd = blockIdx.y;
    const int t = threadIdx.x, l = t & 63, w = t >> 6;
    const size_t base = ((size_t)b * SEQ) * DIM + hd * DH;
    const int lr = l & 15, lk4 = l >> 4;
    const unsigned short* wh = wqkv + (size_t)hd * 12288;

    for (int i = t; i < 197 * 16; i += 512) {
        int s = i >> 4, c4 = i & 15;
        ushort4 v4 = *(const ushort4*)(hbf + base + (size_t)s * DIM + c4 * 4);
        *(ushort4*)(lds + RG_OFF + s * 72 + c4 * 4) = v4;
    }
    if (t < 48) {
        int s = 197 + (t >> 4), c4 = t & 15;
        ushort4 z; z.x = 0; z.y = 0; z.z = 0; z.w = 0;
        *(ushort4*)(lds + RG_OFF + s * 72 + c4 * 4) = z;
    }
    for (int i = t; i < 192 * 16; i += 512) {
        int r = i >> 4, c4 = i & 15;
        ushort4 v4 = *(const ushort4*)(wh + (size_t)r * 64 + c4 * 4);
        *(ushort4*)(lds + WS_OFF + r * 72 + c4 * 4) = v4;
    }
    for (int i = t; i < 64 * 32; i += 512) {
        int d = i >> 5, s2 = 197 + (i & 31);
        if (s2 < 232) lds[VT_OFF + d * 232 + s2] = 0;
    }
    __syncthreads();

    for (int st = w; st < 13; st += 8) {
        bf16x8 a0 = *(const bf16x8*)(lds + RG_OFF + (st * 16 + lr) * 72 + lk4 * 8);
        bf16x8 a1 = *(const bf16x8*)(lds + RG_OFF + (st * 16 + lr) * 72 + 32 + lk4 * 8);
#pragma unroll
        for (int tt = 0; tt < 3; tt++) {
            if (QTMAX == 1 && tt == 0 && st >= QTMAX) continue;
            const float* bias = (tt == 0) ? bq : (tt == 1) ? bk : bv;
#pragma unroll
            for (int et = 0; et < 4; et++) {
                int wrow = (tt * 64 + et * 16 + lr) * 72;
                bf16x8 b0 = *(const bf16x8*)(lds + WS_OFF + wrow + lk4 * 8);
                bf16x8 b1 = *(const bf16x8*)(lds + WS_OFF + wrow + 32 + lk4 * 8);
                f32x4 acc = {0.f, 0.f, 0.f, 0.f};
                acc = mfma16(a0, b0, acc);
                acc = mfma16(a1, b1, acc);
                int e = et * 16 + lr;
                float bval = bias[hd * 64 + e];
#pragma unroll
                for (int r = 0; r < 4; r++) {
                    int s = st * 16 + lk4 * 4 + r;
                    if (s < SEQ) {
                        unsigned short val = f2bf(acc[r] + bval);
                        if (tt == 0) lds[QS_OFF + s * 72 + e] = val;
                        else if (tt == 1) lds[KS_OFF + s * 72 + e] = val;
                        else lds[VT_OFF + e * 232 + s] = val;
                    }
                }
            }
        }
    }
    __syncthreads();

    const int Pb = RG_OFF + w * 3712;
    {
        int jj = 208 + lk4 * 4;
        lds[Pb + lr * 232 + jj + 0] = 0;
        lds[Pb + lr * 232 + jj + 1] = 0;
        lds[Pb + lr * 232 + jj + 2] = 0;
        lds[Pb + lr * 232 + jj + 3] = 0;
    }

    for (int qt = w; qt < QTMAX; qt += 8) {
        int qrow = min(qt * 16 + lr, SEQ - 1);
        bf16x8 q0 = *(const bf16x8*)(lds + QS_OFF + qrow * 72 + lk4 * 8);
        bf16x8 q1 = *(const bf16x8*)(lds + QS_OFF + qrow * 72 + 32 + lk4 * 8);
        f32x4 st_[13];
#pragma unroll
        for (int jt = 0; jt < 13; jt++) st_[jt] = (f32x4){0.f, 0.f, 0.f, 0.f};
#pragma unroll
        for (int jt = 0; jt < 13; jt++) {
            int jrow = min(jt * 16 + lr, SEQ - 1);
            bf16x8 k0 = *(const bf16x8*)(lds + KS_OFF + jrow * 72 + lk4 * 8);
            bf16x8 k1 = *(const bf16x8*)(lds + KS_OFF + jrow * 72 + 32 + lk4 * 8);
            st_[jt] = mfma16(k0, q0, st_[jt]);
            st_[jt] = mfma16(k1, q1, st_[jt]);
        }
        float mx = -1e30f;
#pragma unroll
        for (int jt = 0; jt < 13; jt++)
#pragma unroll
            for (int r = 0; r < 4; r++) {
                int j = jt * 16 + lk4 * 4 + r;
                float sv = st_[jt][r] * 0.125f;
                st_[jt][r] = (j < SEQ) ? sv : -1e30f;
                mx = fmaxf(mx, st_[jt][r]);
            }
        mx = fmaxf(mx, __shfl_xor(mx, 16, 64));
        mx = fmaxf(mx, __shfl_xor(mx, 32, 64));
        float sum = 0.f;
#pragma unroll
        for (int jt = 0; jt < 13; jt++)
#pragma unroll
            for (int r = 0; r < 4; r++) {
                float p = __expf(st_[jt][r] - mx);
                st_[jt][r] = p;
                sum += p;
            }
        sum += __shfl_xor(sum, 16, 64);
        sum += __shfl_xor(sum, 32, 64);
        float inv = 1.0f / sum;
#pragma unroll
        for (int jt = 0; jt < 13; jt++) {
            ushort4 pk;
            pk.x = f2bf(st_[jt][0] * inv); pk.y = f2bf(st_[jt][1] * inv);
            pk.z = f2bf(st_[jt][2] * inv); pk.w = f2bf(st_[jt][3] * inv);
            *(ushort4*)(lds + Pb + lr * 232 + jt * 16 + lk4 * 4) = pk;
        }
        f32x4 acc[4] = {};
#pragma unroll
        for (int kt = 0; kt < 7; kt++) {
            bf16x8 pa = *(const bf16x8*)(lds + Pb + lr * 232 + kt * 32 + lk4 * 8);
#pragma unroll
            for (int nt = 0; nt < 4; nt++) {
                bf16x8 bv8 = *(const bf16x8*)(lds + VT_OFF + (nt * 16 + lr) * 232 + kt * 32 + lk4 * 8);
                acc[nt] = mfma16(pa, bv8, acc[nt]);
            }
        }
#pragma unroll
        for (int nt = 0; nt < 4; nt++)
#pragma unroll
            for (int r = 0; r < 4; r++) {
                int qq = qt * 16 + lk4 * 4 + r;
                if (qq < SEQ) o[base + (size_t)qq * DIM + nt * 16 + lr] = acc[nt][r];
            }
    }
}

// ======== MLP1 GEMM: 128(M)x256(N) tile, 2-phase counted-vmcnt dbuf, gelu->bf16 ========
// 256 threads, 4 waves as 2(M)x2(N); wave tile 64x128. LDS 48KB. Grid (N/256, M/128).
__global__ __launch_bounds__(256) void gemm_mlp1(const unsigned short* __restrict__ A,
                                                 const unsigned short* __restrict__ Bw,
                                                 const float* __restrict__ bias,
                                                 unsigned short* __restrict__ Cbf,
                                                 int M, int N, int K) {
    __shared__ __align__(16) unsigned short As[2][128 * 32];
    __shared__ __align__(16) unsigned short Bs[2][256 * 32];
    const int t = threadIdx.x, l = t & 63, w = t >> 6;
    const int bn = blockIdx.x * 256, bm = blockIdx.y * 128;
    const int wr = w >> 1, wc = w & 1;
    f32x4 acc[4][8] = {};

    const int rbase = t >> 2, kofs = (t & 3) * 8;
    const unsigned short* Ar0 = A + (size_t)min(bm + rbase, M - 1) * K + kofs;
    const unsigned short* Ar1 = A + (size_t)min(bm + 64 + rbase, M - 1) * K + kofs;
    const unsigned short* Br0 = Bw + (size_t)(bn + rbase) * K + kofs;
    const unsigned short* Br1 = Bw + (size_t)(bn + 64 + rbase) * K + kofs;
    const unsigned short* Br2 = Bw + (size_t)(bn + 128 + rbase) * K + kofs;
    const unsigned short* Br3 = Bw + (size_t)(bn + 192 + rbase) * K + kofs;
    const int ldst = t * 8;   // hw offset within a 2048-hw (64-row) issue segment
    const int lr = l & 15, lk = (l >> 4) * 8;

#define MLP1_STAGE(buf, k0)                                  \
    do {                                                     \
        gload_lds16(Ar0 + (k0), As[buf] + ldst);             \
        gload_lds16(Ar1 + (k0), As[buf] + 2048 + ldst);      \
        gload_lds16(Br0 + (k0), Bs[buf] + ldst);             \
        gload_lds16(Br1 + (k0), Bs[buf] + 2048 + ldst);      \
        gload_lds16(Br2 + (k0), Bs[buf] + 4096 + ldst);      \
        gload_lds16(Br3 + (k0), Bs[buf] + 6144 + ldst);      \
    } while (0)

    MLP1_STAGE(0, 0);
    int cur = 0;
    for (int k0 = 0; k0 < K; k0 += 32) {
        if (k0 + 32 < K) {
            MLP1_STAGE(cur ^ 1, k0 + 32);
            WAIT_VMCNT_6();
        } else {
            WAIT_VMCNT_0();
        }
        BARRIER_RAW();
        bf16x8 a[4], bfr[8];
#pragma unroll
        for (int m = 0; m < 4; m++)
            a[m] = *(const bf16x8*)(As[cur] + (wr * 64 + m * 16 + lr) * 32 + lk);
#pragma unroll
        for (int n = 0; n < 8; n++)
            bfr[n] = *(const bf16x8*)(Bs[cur] + (wc * 128 + n * 16 + lr) * 32 + lk);
#pragma unroll
        for (int m = 0; m < 4; m++)
#pragma unroll
            for (int n = 0; n < 8; n++)
                acc[m][n] = mfma16(a[m], bfr[n], acc[m][n]);
        BARRIER_RAW();
        cur ^= 1;
    }
#undef MLP1_STAGE

#pragma unroll
    for (int m = 0; m < 4; m++) {
#pragma unroll
        for (int r = 0; r < 4; r++) {
            int gm = bm + wr * 64 + m * 16 + (l >> 4) * 4 + r;
            if (gm >= M) continue;
#pragma unroll
            for (int n = 0; n < 8; n++) {
                int gn = bn + wc * 128 + n * 16 + lr;
                float vb = acc[m][n][r] + bias[gn];
                float gl = 0.5f * vb * (1.0f + erff(vb * 0.70710678118f));
                Cbf[(size_t)gm * N + gn] = f2bf(gl);
            }
        }
    }
}

// ---------------- split-K NT GEMM: partials[z][m][n], K chunk = KFULL/SPLITK ----------------
__global__ __launch_bounds__(256) void gemm_splitk(const unsigned short* __restrict__ A,
                                                   const unsigned short* __restrict__ Bw,
                                                   float* __restrict__ parts,
                                                   int M, int N, int KFULL) {
    __shared__ __align__(16) unsigned short As[2][128 * 32];
    __shared__ __align__(16) unsigned short Bs[2][128 * 32];
    const int t = threadIdx.x, l = t & 63, w = t >> 6;
    const int bm = blockIdx.x * 128, bn = blockIdx.y * 128;
    const int KC = KFULL / SPLITK;
    const int kbeg = blockIdx.z * KC;
    const int wr = w >> 1, wc = w & 1;
    f32x4 acc[4][4] = {};

    const int ra0 = t >> 2, ka0 = (t & 3) * 8;
    const int ra1 = (t + 256) >> 2, ka1 = ((t + 256) & 3) * 8;
    const unsigned short* Ar0 = A + (size_t)min(bm + ra0, M - 1) * KFULL + kbeg + ka0;
    const unsigned short* Ar1 = A + (size_t)min(bm + ra1, M - 1) * KFULL + kbeg + ka1;
    const unsigned short* Br0 = Bw + (size_t)(bn + ra0) * KFULL + kbeg + ka0;
    const unsigned short* Br1 = Bw + (size_t)(bn + ra1) * KFULL + kbeg + ka1;
    const int lo0 = (0 * 256 + w * 64) * 8, lo1 = (1 * 256 + w * 64) * 8;
    const int lr = l & 15, lk = (l >> 4) * 8;

    gload_lds16(Ar0, As[0] + lo0);
    gload_lds16(Ar1, As[0] + lo1);
    gload_lds16(Br0, Bs[0] + lo0);
    gload_lds16(Br1, Bs[0] + lo1);
    int cur = 0;
    for (int k0 = 0; k0 < KC; k0 += 32) {
        if (k0 + 32 < KC) {
            gload_lds16(Ar0 + k0 + 32, As[cur ^ 1] + lo0);
            gload_lds16(Ar1 + k0 + 32, As[cur ^ 1] + lo1);
            gload_lds16(Br0 + k0 + 32, Bs[cur ^ 1] + lo0);
            gload_lds16(Br1 + k0 + 32, Bs[cur ^ 1] + lo1);
            WAIT_VMCNT_4();
        } else {
            WAIT_VMCNT_0();
        }
        BARRIER_RAW();
        bf16x8 a[4], bfr[4];
#pragma unroll
        for (int m = 0; m < 4; m++)
            a[m] = *(const bf16x8*)(As[cur] + (wr * 64 + m * 16 + lr) * 32 + lk);
#pragma unroll
        for (int n = 0; n < 4; n++)
            bfr[n] = *(const bf16x8*)(Bs[cur] + (wc * 64 + n * 16 + lr) * 32 + lk);
#pragma unroll
        for (int m = 0; m < 4; m++)
#pragma unroll
            for (int n = 0; n < 4; n++)
                acc[m][n] = mfma16(a[m], bfr[n], acc[m][n]);
        BARRIER_RAW();
        cur ^= 1;
    }

    float* po = parts + (size_t)blockIdx.z * M * N;
#pragma unroll
    for (int m = 0; m < 4; m++) {
#pragma unroll
        for (int r = 0; r < 4; r++) {
            int gm = bm + wr * 64 + m * 16 + (l >> 4) * 4 + r;
            if (gm >= M) continue;
#pragma unroll
            for (int n = 0; n < 4; n++) {
                int gn = bn + wc * 64 + n * 16 + lr;
                po[(size_t)gm * N + gn] = acc[m][n][r];
            }
        }
    }
}

// ---------------- fallback 128x128 BK=32 GEMM (small-ws path) ----------------
template <int MODE, int SWAPXY>
__global__ __launch_bounds__(256) void gemm_bf(const unsigned short* __restrict__ A,
                                               const unsigned short* __restrict__ Bw,
                                               const float* __restrict__ bias,
                                               void* __restrict__ Cout,
                                               const float* __restrict__ res,
                                               int M, int N, int K) {
    __shared__ __align__(16) unsigned short As[2][128 * 32];
    __shared__ __align__(16) unsigned short Bs[2][128 * 32];
    const int t = threadIdx.x, l = t & 63, w = t >> 6;
    const int bm = (SWAPXY ? blockIdx.y : blockIdx.x) * 128;
    const int bn = (SWAPXY ? blockIdx.x : blockIdx.y) * 128;
    const int wr = w >> 1, wc = w & 1;
    f32x4 acc[4][4] = {};

    const int ra0 = t >> 2, ka0 = (t & 3) * 8;
    const int ra1 = (t + 256) >> 2, ka1 = ((t + 256) & 3) * 8;
    const unsigned short* Ar0 = A + (size_t)min(bm + ra0, M - 1) * K + ka0;
    const unsigned short* Ar1 = A + (size_t)min(bm + ra1, M - 1) * K + ka1;
    const unsigned short* Br0 = Bw + (size_t)(bn + ra0) * K + ka0;
    const unsigned short* Br1 = Bw + (size_t)(bn + ra1) * K + ka1;
    const int lo0 = (0 * 256 + w * 64) * 8, lo1 = (1 * 256 + w * 64) * 8;
    const int lr = l & 15, lk = (l >> 4) * 8;

    gload_lds16(Ar0, As[0] + lo0);
    gload_lds16(Ar1, As[0] + lo1);
    gload_lds16(Br0, Bs[0] + lo0);
    gload_lds16(Br1, Bs[0] + lo1);
    int cur = 0;
    for (int k0 = 0; k0 < K; k0 += 32) {
        if (k0 + 32 < K) {
            gload_lds16(Ar0 + k0 + 32, As[cur ^ 1] + lo0);
            gload_lds16(Ar1 + k0 + 32, As[cur ^ 1] + lo1);
            gload_lds16(Br0 + k0 + 32, Bs[cur ^ 1] + lo0);
            gload_lds16(Br1 + k0 + 32, Bs[cur ^ 1] + lo1);
            WAIT_VMCNT_4();
        } else {
            WAIT_VMCNT_0();
        }
        BARRIER_RAW();
        bf16x8 a[4], bfr[4];
#pragma unroll
        for (int m = 0; m < 4; m++)
            a[m] = *(const bf16x8*)(As[cur] + (wr * 64 + m * 16 + lr) * 32 + lk);
#pragma unroll
        for (int n = 0; n < 4; n++)
            bfr[n] = *(const bf16x8*)(Bs[cur] + (wc * 64 + n * 16 + lr) * 32 + lk);
#pragma unroll
        for (int m = 0; m < 4; m++)
#pragma unroll
            for (int n = 0; n < 4; n++)
                acc[m][n] = mfma16(a[m], bfr[n], acc[m][n]);
        BARRIER_RAW();
        cur ^= 1;
    }

#pragma unroll
    for (int m = 0; m < 4; m++) {
#pragma unroll
        for (int r = 0; r < 4; r++) {
            int gm = bm + wr * 64 + m * 16 + (l >> 4) * 4 + r;
            if (gm >= M) continue;
#pragma unroll
            for (int n = 0; n < 4; n++) {
                int gn = bn + wc * 64 + n * 16 + lr;
                float vb = acc[m][n][r] + bias[gn];
                if (MODE == 1) {
                    float gl = 0.5f * vb * (1.0f + erff(vb * 0.70710678118f));
                    ((unsigned short*)Cout)[(size_t)gm * N + gn] = f2bf(gl);
                } else {
                    ((float*)Cout)[(size_t)gm * N + gn] = vb + res[(size_t)gm * N + gn];
                }
            }
        }
    }
}

// ---------------- classifier head (folds last-layer split-K partials + b2) ----------------
__global__ __launch_bounds__(256) void head_kernel(const float* __restrict__ x,
                                                   const float* __restrict__ Wh,
                                                   const float* __restrict__ bh,
                                                   float* __restrict__ logits,
                                                   const float* __restrict__ cparts,
                                                   const float* __restrict__ b2l) {
    __shared__ float xs[768];
    int b = blockIdx.x;
    int tid = threadIdx.x;
#pragma unroll
    for (int i = 0; i < 3; i++) {
        int c = tid + i * 256;
        float v = x[(size_t)b * SEQ * DIM + c];
        if (cparts) {
            v += b2l[c];
#pragma unroll
            for (int kc = 0; kc < SPLITK; kc++)
                v += cparts[((size_t)kc * NBATCH + b) * DIM + c];
        }
        xs[c] = v;
    }
    __syncthreads();
    int wave = tid >> 6, lane = tid & 63;
    int o = blockIdx.y * 4 + wave;
    if (o < NOUT) {
        float acc = 0;
#pragma unroll
        for (int t = 0; t < 12; t++) {
            int d = lane + t * 64;
            acc = fmaf(xs[d], Wh[(size_t)o * DIM + d], acc);
        }
#pragma unroll
        for (int off = 32; off > 0; off >>= 1) acc += __shfl_down(acc, off, 64);
        if (lane == 0) logits[b * NOUT + o] = acc + bh[o];
    }
}

__global__ __launch_bounds__(256) void softmax_kernel(const float* __restrict__ logits,
                                                      float* __restrict__ out) {
    __shared__ float tmp[4];
    int b = blockIdx.x, tid = threadIdx.x;
    float vals[4];
    float mx = -1e30f;
#pragma unroll
    for (int i = 0; i < 4; i++) {
        int c = tid + i * 256;
        vals[i] = (c < NOUT) ? logits[b * NOUT + c] : -1e30f;
        mx = fmaxf(mx, vals[i]);
    }
#pragma unroll
    for (int o = 32; o > 0; o >>= 1) mx = fmaxf(mx, __shfl_down(mx, o, 64));
    int wave = tid >> 6, lane = tid & 63;
    __syncthreads();
    if (lane == 0) tmp[wave] = mx;
    __syncthreads();
    mx = fmaxf(fmaxf(tmp[0], tmp[1]), fmaxf(tmp[2], tmp[3]));
    float s = 0;
#pragma unroll
    for (int i = 0; i < 4; i++) {
        int c = tid + i * 256;
        if (c < NOUT) {
            vals[i] = __expf(vals[i] - mx);
            s += vals[i];
        } else vals[i] = 0.f;
    }
#pragma unroll
    for (int o = 32; o > 0; o >>= 1) s += __shfl_down(s, o, 64);
    __syncthreads();
    if (lane == 0) tmp[wave] = s;
    __syncthreads();
    s = tmp[0] + tmp[1] + tmp[2] + tmp[3];
    float invs = 1.0f / s;
#pragma unroll
    for (int i = 0; i < 4; i++) {
        int c = tid + i * 256;
        if (c < NOUT) out[b * NOUT + c] = vals[i] * invs;
    }
}

extern "C" void kernel_launch(void* const* d_in, const int* in_sizes, int n_in,
                              void* d_out, int out_size, void* d_ws, size_t ws_size,
                              hipStream_t stream) {
    const float* images = (const float*)d_in[0];
    const float* Wp   = (const float*)d_in[1];
    const float* bp   = (const float*)d_in[2];
    const float* cls  = (const float*)d_in[3];
    const float* pos  = (const float*)d_in[4];
    const float* ln1g = (const float*)d_in[5];
    const float* ln1b = (const float*)d_in[6];
    const float* Wq   = (const float*)d_in[7];
    const float* bq   = (const float*)d_in[8];
    const float* Wk   = (const float*)d_in[9];
    const float* bk   = (const float*)d_in[10];
    const float* Wv   = (const float*)d_in[11];
    const float* bv   = (const float*)d_in[12];
    const float* ln2g = (const float*)d_in[13];
    const float* ln2b = (const float*)d_in[14];
    const float* W1   = (const float*)d_in[15];
    const float* b1   = (const float*)d_in[16];
    const float* W2   = (const float*)d_in[17];
    const float* b2   = (const float*)d_in[18];
    const float* Wh   = (const float*)d_in[19];
    const float* bh   = (const float*)d_in[20];
    float* out = (float*)d_out;

    const size_t NX = (size_t)MROWS * DIM;              // 4,841,472
    const size_t NIMG = (size_t)NBATCH * 3 * 224 * 224; // 4,816,896
    const size_t NW = (size_t)MDIM * DIM;               // 2,359,296 per layer

    char* p = (char*)d_ws;
    float* x      = (float*)p;            p += NX * 4;
    float* h      = (float*)p;            p += NX * 4;
    float* logits = (float*)p;            p += (size_t)NBATCH * NOUT * 4;
    unsigned short* hbf   = (unsigned short*)p; p += NX * 2;
    unsigned short* h2bf  = (unsigned short*)p; p += NX * 2;
    unsigned short* mid   = (unsigned short*)p; p += (size_t)MROWS * MDIM * 2;
    unsigned short* wqkvb = (unsigned short*)p; p += (size_t)NLAYER * NHEAD * 12288 * 2;
    unsigned short* imgbf = (unsigned short*)p; p += NIMG * 2;
    unsigned short* wpbf  = (unsigned short*)p; p += (size_t)DIM * DIM * 2;

    size_t used = (size_t)(p - (char*)d_ws);
    bool skq = ws_size >= used + (size_t)SPLITK * NX * 4;
    float* parts = (float*)p;
    if (skq) p += (size_t)SPLITK * NX * 4;
    used = (size_t)(p - (char*)d_ws);
    bool big = ws_size >= used + (size_t)2 * NLAYER * NW * 2;
    unsigned short* w1a = (unsigned short*)p;
    unsigned short* w2a = big ? w1a + (size_t)NLAYER * NW : w1a + NW;

    cls_pos_kernel<<<dim3(NBATCH), dim3(256), 0, stream>>>(cls, pos, x);
    cvt4<<<dim3(2048), dim3(256), 0, stream>>>(images, imgbf, (int)(NIMG / 4));
    cvt4<<<dim3(576), dim3(256), 0, stream>>>(Wp, wpbf, (int)(DIM * DIM / 4));
    cvt_qkvw<<<dim3(1024), dim3(256), 0, stream>>>(Wq, Wk, Wv, wqkvb);
    gemm_patch_bf<<<dim3(49, 6), dim3(256), 0, stream>>>(imgbf, wpbf, bp, pos, x);
    if (big) {
        cvt4<<<dim3(2048), dim3(256), 0, stream>>>(W1, w1a, (int)(NLAYER * NW / 4));
        cvt4<<<dim3(2048), dim3(256), 0, stream>>>(W2, w2a, (int)(NLAYER * NW / 4));
    }

    for (int l = 0; l < NLAYER; l++) {
        const unsigned short* wl1 = big ? w1a + (size_t)l * NW : w1a;
        const unsigned short* wl2 = big ? w2a + (size_t)l * NW : w2a;
        if (!big) {
            cvt4<<<dim3(2048), dim3(256), 0, stream>>>(W1 + (size_t)l * NW, w1a, (int)(NW / 4));
            cvt4<<<dim3(2048), dim3(256), 0, stream>>>(W2 + (size_t)l * NW, w1a + NW, (int)(NW / 4));
        }
        if (skq && l > 0) {
            ln_wave<0, 1><<<dim3(MROWS / 4), dim3(256), 0, stream>>>(
                x, nullptr, x, hbf, ln1g + l * DIM, ln1b + l * DIM, parts, b2 + (l - 1) * DIM, 1);
        } else {
            ln_wave<0, 0><<<dim3(MROWS / 4), dim3(256), 0, stream>>>(
                x, nullptr, nullptr, hbf, ln1g + l * DIM, ln1b + l * DIM, nullptr, nullptr, 1);
        }
        bool last = skq && (l == NLAYER - 1);
        if (last) {
            fused_attn<1><<<dim3(NBATCH, NHEAD), dim3(512), 0, stream>>>(
                hbf, wqkvb + (size_t)l * NHEAD * 12288,
                bq + l * NHEAD * DH, bk + l * NHEAD * DH, bv + l * NHEAD * DH, h);
            ln_wave<1, 0><<<dim3(NBATCH / 4), dim3(256), 0, stream>>>(
                x, h, x, h2bf, ln2g + l * DIM, ln2b + l * DIM, nullptr, nullptr, SEQ);
            gemm_mlp1<<<dim3(12, 1), dim3(256), 0, stream>>>(
                h2bf, wl1, b1 + l * MDIM, mid, NBATCH, MDIM, DIM);
            gemm_splitk<<<dim3(1, 6, SPLITK), dim3(256), 0, stream>>>(
                mid, wl2, parts, NBATCH, DIM, MDIM);
        } else {
            fused_attn<13><<<dim3(NBATCH, NHEAD), dim3(512), 0, stream>>>(
                hbf, wqkvb + (size_t)l * NHEAD * 12288,
                bq + l * NHEAD * DH, bk + l * NHEAD * DH, bv + l * NHEAD * DH, h);
            ln_wave<1, 0><<<dim3(MROWS / 4), dim3(256), 0, stream>>>(
                x, h, x, h2bf, ln2g + l * DIM, ln2b + l * DIM, nullptr, nullptr, 1);
            gemm_mlp1<<<dim3(12, 50), dim3(256), 0, stream>>>(
                h2bf, wl1, b1 + l * MDIM, mid, MROWS, MDIM, DIM);
            if (skq) {
                gemm_splitk<<<dim3(50, 6, SPLITK), dim3(256), 0, stream>>>(
                    mid, wl2, parts, MROWS, DIM, MDIM);
            } else {
                gemm_bf<2, 0><<<dim3(50, 6), dim3(256), 0, stream>>>(
                    mid, wl2, b2 + l * DIM, x, x, MROWS, DIM, MDIM);
            }
        }
    }

    head_kernel<<<dim3(NBATCH, 250), dim3(256), 0, stream>>>(
        x, Wh, bh, logits,
        skq ? parts : nullptr, skq ? b2 + (NLAYER - 1) * DIM : nullptr);
    softmax_kernel<<<dim3(NBATCH), dim3(256), 0, stream>>>(logits, out);
}

// Round 13
// 2146.543 us; speedup vs baseline: 1.3709x; 1.3709x over previous
//
#include <hip/hip_runtime.h>
#include <math.h>
#include <stdint.h>

#define NBATCH 32
#define SEQ 197
#define DIM 768
#define NHEAD 12
#define DH 64
#define MDIM 3072
#define NLAYER 12
#define NPATCH 196
#define NOUT 1000
#define MROWS (NBATCH * SEQ)   // 6304
#define SPLITK 2

typedef __bf16 bf16x8 __attribute__((ext_vector_type(8)));
typedef float f32x4 __attribute__((ext_vector_type(4)));

__device__ __forceinline__ unsigned short f2bf(float f) {
    unsigned u = __float_as_uint(f);
    unsigned r = u + 0x7fffu + ((u >> 16) & 1u);
    return (unsigned short)(r >> 16);
}

__device__ __forceinline__ f32x4 mfma16(bf16x8 a, bf16x8 b, f32x4 c) {
    return __builtin_amdgcn_mfma_f32_16x16x32_bf16(a, b, c, 0, 0, 0);
}

// async global->LDS 16B: lds pointer wave-uniform base; HW writes lane l at base + l*16.
__device__ __forceinline__ void gload_lds16(const void* g, const void* lds) {
    __builtin_amdgcn_global_load_lds(
        (const __attribute__((address_space(1))) void*)(uintptr_t)g,
        (__attribute__((address_space(3))) void*)(uint32_t)(uintptr_t)lds,
        16, 0, 0);
}

#define WAIT_VMCNT_4() asm volatile("s_waitcnt vmcnt(4)" ::: "memory")
#define WAIT_VMCNT_0() asm volatile("s_waitcnt vmcnt(0)" ::: "memory")
#define BARRIER_RAW()                      \
    do {                                   \
        asm volatile("" ::: "memory");     \
        __builtin_amdgcn_s_barrier();      \
        asm volatile("" ::: "memory");     \
    } while (0)

// ---------------- fp32 -> bf16 converter (grid-stride) ----------------
__global__ __launch_bounds__(256) void cvt4(const float* __restrict__ src,
                                            unsigned short* __restrict__ dst, int n4) {
    int stride = gridDim.x * 256;
    for (int i = blockIdx.x * 256 + threadIdx.x; i < n4; i += stride) {
        float4 f = *(const float4*)(src + (size_t)i * 4);
        ushort4 o;
        o.x = f2bf(f.x); o.y = f2bf(f.y); o.z = f2bf(f.z); o.w = f2bf(f.w);
        *(ushort4*)(dst + (size_t)i * 4) = o;
    }
}

// gather Wq/Wk/Wv [L][H][e][d] -> wqkvb [L][H][3*64 rows][64] bf16
__global__ __launch_bounds__(256) void cvt_qkvw(const float* __restrict__ Wq,
                                                const float* __restrict__ Wk,
                                                const float* __restrict__ Wv,
                                                unsigned short* __restrict__ dst) {
    const int n = NLAYER * NHEAD * 3 * 64 * 64;
    int stride = gridDim.x * 256;
    for (int i = blockIdx.x * 256 + threadIdx.x; i < n; i += stride) {
        int d = i & 63, e = (i >> 6) & 63;
        int v = i >> 12;
        int t = v % 3, hh = (v / 3) % NHEAD, l = v / (3 * NHEAD);
        const float* src = (t == 0) ? Wq : (t == 1) ? Wk : Wv;
        dst[i] = f2bf(src[(((size_t)(l * NHEAD + hh)) * 64 + e) * 64 + d]);
    }
}

// ---------------- cls + pos init ----------------
__global__ __launch_bounds__(256) void cls_pos_kernel(const float* __restrict__ cls,
                                                      const float* __restrict__ pos,
                                                      float* __restrict__ x) {
    int b = blockIdx.x, tid = threadIdx.x;
#pragma unroll
    for (int i = 0; i < 3; i++) {
        int c = tid + i * 256;
        x[(size_t)b * SEQ * DIM + c] = cls[c] + pos[c];
    }
}

// ---------------- patch-embed GEMM: bf16 MFMA, gathered A, counted-vmcnt dbuf ----------------
__global__ __launch_bounds__(256) void gemm_patch_bf(const unsigned short* __restrict__ imgbf,
                                                     const unsigned short* __restrict__ wpbf,
                                                     const float* __restrict__ bp,
                                                     const float* __restrict__ pos,
                                                     float* __restrict__ x) {
    __shared__ __align__(16) unsigned short As[2][128 * 32];
    __shared__ __align__(16) unsigned short Bs[2][128 * 32];
    const int t = threadIdx.x, l = t & 63, w = t >> 6;
    const int bm = blockIdx.x * 128, bn = blockIdx.y * 128;
    const int wr = w >> 1, wc = w & 1;
    f32x4 acc[4][4] = {};

    const int ra0 = t >> 2, ka0 = (t & 3) * 8;
    const int ra1 = (t + 256) >> 2, ka1 = ((t + 256) & 3) * 8;
    int gm0 = bm + ra0, b0 = gm0 / NPATCH, p0 = gm0 % NPATCH;
    int gm1 = bm + ra1, b1 = gm1 / NPATCH, p1 = gm1 % NPATCH;
    const unsigned short* ib0 =
        imgbf + ((size_t)b0 * 3 * 224 + (size_t)(p0 / 14) * 16) * 224 + (p0 % 14) * 16;
    const unsigned short* ib1 =
        imgbf + ((size_t)b1 * 3 * 224 + (size_t)(p1 / 14) * 16) * 224 + (p1 % 14) * 16;
    const unsigned short* Br0 = wpbf + (size_t)(bn + ra0) * 768 + ka0;
    const unsigned short* Br1 = wpbf + (size_t)(bn + ra1) * 768 + ka1;
    const int lA0 = (0 * 256 + w * 64) * 8, lA1 = (1 * 256 + w * 64) * 8;
    const int lr = l & 15, lk = (l >> 4) * 8;

#define PATCH_STAGE(buf, k0)                                                   \
    {                                                                          \
        int kA0 = (k0) + ka0, kA1 = (k0) + ka1;                                \
        int c0 = kA0 >> 8, i0 = (kA0 >> 4) & 15, j0 = kA0 & 15;                \
        int c1 = kA1 >> 8, i1 = (kA1 >> 4) & 15, j1 = kA1 & 15;                \
        gload_lds16(ib0 + ((size_t)c0 * 224 + i0) * 224 + j0, As[buf] + lA0);  \
        gload_lds16(ib1 + ((size_t)c1 * 224 + i1) * 224 + j1, As[buf] + lA1);  \
        gload_lds16(Br0 + (k0), Bs[buf] + lA0);                                \
        gload_lds16(Br1 + (k0), Bs[buf] + lA1);                                \
    }

    PATCH_STAGE(0, 0);
    int cur = 0;
    for (int k0 = 0; k0 < 768; k0 += 32) {
        if (k0 + 32 < 768) {
            PATCH_STAGE(cur ^ 1, k0 + 32);
            WAIT_VMCNT_4();
        } else {
            WAIT_VMCNT_0();
        }
        BARRIER_RAW();
        bf16x8 a[4], bfr[4];
#pragma unroll
        for (int m = 0; m < 4; m++)
            a[m] = *(const bf16x8*)(As[cur] + (wr * 64 + m * 16 + lr) * 32 + lk);
#pragma unroll
        for (int n = 0; n < 4; n++)
            bfr[n] = *(const bf16x8*)(Bs[cur] + (wc * 64 + n * 16 + lr) * 32 + lk);
#pragma unroll
        for (int m = 0; m < 4; m++)
#pragma unroll
            for (int n = 0; n < 4; n++)
                acc[m][n] = mfma16(a[m], bfr[n], acc[m][n]);
        BARRIER_RAW();
        cur ^= 1;
    }
#undef PATCH_STAGE

#pragma unroll
    for (int m = 0; m < 4; m++) {
#pragma unroll
        for (int r = 0; r < 4; r++) {
            int gm = bm + wr * 64 + m * 16 + (l >> 4) * 4 + r;
            int b2 = gm / NPATCH, p2 = gm % NPATCH;
            size_t orow = (size_t)(b2 * SEQ + 1 + p2) * DIM;
#pragma unroll
            for (int n = 0; n < 4; n++) {
                int gn = bn + wc * 64 + n * 16 + lr;
                x[orow + gn] = acc[m][n][r] + bp[gn] + pos[(size_t)(1 + p2) * DIM + gn];
            }
        }
    }
}

// ---------------- wave-per-row LayerNorm, bf16 h out ----------------
template <int RES, int RED>
__global__ __launch_bounds__(256) void ln_wave(const float* __restrict__ x_in,
                                               const float* __restrict__ addv,
                                               float* __restrict__ x_out,
                                               unsigned short* __restrict__ h_out,
                                               const float* __restrict__ g,
                                               const float* __restrict__ bb,
                                               const float* __restrict__ parts,
                                               const float* __restrict__ badd,
                                               int xmul) {
    int w = threadIdx.x >> 6, l = threadIdx.x & 63;
    size_t row = (size_t)blockIdx.x * 4 + w;
    size_t xrow = row * xmul;
    const float* xr = x_in + xrow * DIM;
    float4 v[3];
    float s = 0.f;
#pragma unroll
    for (int u = 0; u < 3; u++) {
        int c = u * 256 + l * 4;
        v[u] = *(const float4*)(xr + c);
        if (RES) {
            float4 a4 = *(const float4*)(addv + xrow * DIM + c);
            v[u].x += a4.x; v[u].y += a4.y; v[u].z += a4.z; v[u].w += a4.w;
        }
        if (RED) {
            float4 b4 = *(const float4*)(badd + c);
            v[u].x += b4.x; v[u].y += b4.y; v[u].z += b4.z; v[u].w += b4.w;
#pragma unroll
            for (int kc = 0; kc < SPLITK; kc++) {
                float4 p4 = *(const float4*)(parts + ((size_t)kc * MROWS + row) * DIM + c);
                v[u].x += p4.x; v[u].y += p4.y; v[u].z += p4.z; v[u].w += p4.w;
            }
        }
        s += v[u].x + v[u].y + v[u].z + v[u].w;
    }
#pragma unroll
    for (int o = 1; o < 64; o <<= 1) s += __shfl_xor(s, o, 64);
    float mean = s * (1.0f / 768.0f);
    float s2 = 0.f;
#pragma unroll
    for (int u = 0; u < 3; u++) {
        float dx = v[u].x - mean, dy = v[u].y - mean, dz = v[u].z - mean, dw = v[u].w - mean;
        s2 += dx * dx + dy * dy + dz * dz + dw * dw;
    }
#pragma unroll
    for (int o = 1; o < 64; o <<= 1) s2 += __shfl_xor(s2, o, 64);
    float inv = rsqrtf(s2 * (1.0f / 768.0f) + 1e-5f);
#pragma unroll
    for (int u = 0; u < 3; u++) {
        int c = u * 256 + l * 4;
        float4 g4 = *(const float4*)(g + c);
        float4 b4 = *(const float4*)(bb + c);
        ushort4 o;
        o.x = f2bf((v[u].x - mean) * inv * g4.x + b4.x);
        o.y = f2bf((v[u].y - mean) * inv * g4.y + b4.y);
        o.z = f2bf((v[u].z - mean) * inv * g4.z + b4.z);
        o.w = f2bf((v[u].w - mean) * inv * g4.w + b4.w);
        *(ushort4*)(h_out + row * DIM + c) = o;
        if (RES || RED) *(float4*)(x_out + xrow * DIM + c) = v[u];
    }
}

// ================= fused QKV projection + attention =================
// One block per (b, head), 512 threads (8 waves). LDS 146.7KB flat, region-aliased.
// Each wave handles q-tiles w and w+8 with a SHARED QK^T loop (K fragments read once).
#define KS_OFF 0
#define QS_OFF 14400
#define VT_OFF 28800
#define RG_OFF 43648
#define WS_OFF (RG_OFF + 14400)

// softmax (in-register) + P->LDS + PV + O-write for one q-tile
#define SOFTMAX_PV(ST, QT)                                                              \
    do {                                                                                \
        float mx = -1e30f;                                                              \
        _Pragma("unroll") for (int jt = 0; jt < 13; jt++)                               \
            _Pragma("unroll") for (int r = 0; r < 4; r++) {                             \
                int j = jt * 16 + lk4 * 4 + r;                                          \
                float sv = ST[jt][r] * 0.125f;                                          \
                ST[jt][r] = (j < SEQ) ? sv : -1e30f;                                    \
                mx = fmaxf(mx, ST[jt][r]);                                              \
            }                                                                           \
        mx = fmaxf(mx, __shfl_xor(mx, 16, 64));                                         \
        mx = fmaxf(mx, __shfl_xor(mx, 32, 64));                                         \
        float sum = 0.f;                                                                \
        _Pragma("unroll") for (int jt = 0; jt < 13; jt++)                               \
            _Pragma("unroll") for (int r = 0; r < 4; r++) {                             \
                float pv_ = __expf(ST[jt][r] - mx);                                     \
                ST[jt][r] = pv_;                                                        \
                sum += pv_;                                                             \
            }                                                                           \
        sum += __shfl_xor(sum, 16, 64);                                                 \
        sum += __shfl_xor(sum, 32, 64);                                                 \
        float inv_ = 1.0f / sum;                                                        \
        _Pragma("unroll") for (int jt = 0; jt < 13; jt++) {                             \
            ushort4 pk;                                                                 \
            pk.x = f2bf(ST[jt][0] * inv_); pk.y = f2bf(ST[jt][1] * inv_);               \
            pk.z = f2bf(ST[jt][2] * inv_); pk.w = f2bf(ST[jt][3] * inv_);               \
            *(ushort4*)(lds + Pb + lr * 232 + jt * 16 + lk4 * 4) = pk;                  \
        }                                                                               \
        f32x4 oacc[4] = {};                                                             \
        __builtin_amdgcn_s_setprio(1);                                                  \
        _Pragma("unroll") for (int kt = 0; kt < 7; kt++) {                              \
            bf16x8 pa = *(const bf16x8*)(lds + Pb + lr * 232 + kt * 32 + lk4 * 8);      \
            _Pragma("unroll") for (int nt = 0; nt < 4; nt++) {                          \
                bf16x8 bv8 = *(const bf16x8*)(lds + VT_OFF + (nt * 16 + lr) * 232 +     \
                                              kt * 32 + lk4 * 8);                      \
                oacc[nt] = mfma16(pa, bv8, oacc[nt]);                                   \
            }                                                                           \
        }                                                                               \
        __builtin_amdgcn_s_setprio(0);                                                  \
        _Pragma("unroll") for (int nt = 0; nt < 4; nt++)                                \
            _Pragma("unroll") for (int r = 0; r < 4; r++) {                             \
                int qq = (QT) * 16 + lk4 * 4 + r;                                       \
                if (qq < SEQ) o[base + (size_t)qq * DIM + nt * 16 + lr] = oacc[nt][r];  \
            }                                                                           \
    } while (0)

template <int QTMAX>
__global__ __launch_bounds__(512) void fused_attn(const unsigned short* __restrict__ hbf,
                                                  const unsigned short* __restrict__ wqkv,
                                                  const float* __restrict__ bq,
                                                  const float* __restrict__ bk,
                                                  const float* __restrict__ bv,
                                                  float* __restrict__ o) {
    __shared__ __align__(16) unsigned short lds[73344];
    const int b = blockIdx.x, hd = blockIdx.y;
    const int t = threadIdx.x, l = t & 63, w = t >> 6;
    const size_t base = ((size_t)b * SEQ) * DIM + hd * DH;
    const int lr = l & 15, lk4 = l >> 4;
    const unsigned short* wh = wqkv + (size_t)hd * 12288;

    for (int i = t; i < 197 * 16; i += 512) {
        int s = i >> 4, c4 = i & 15;
        ushort4 v4 = *(const ushort4*)(hbf + base + (size_t)s * DIM + c4 * 4);
        *(ushort4*)(lds + RG_OFF + s * 72 + c4 * 4) = v4;
    }
    if (t < 48) {
        int s = 197 + (t >> 4), c4 = t & 15;
        ushort4 z; z.x = 0; z.y = 0; z.z = 0; z.w = 0;
        *(ushort4*)(lds + RG_OFF + s * 72 + c4 * 4) = z;
    }
    for (int i = t; i < 192 * 16; i += 512) {
        int r = i >> 4, c4 = i & 15;
        ushort4 v4 = *(const ushort4*)(wh + (size_t)r * 64 + c4 * 4);
        *(ushort4*)(lds + WS_OFF + r * 72 + c4 * 4) = v4;
    }
    for (int i = t; i < 64 * 32; i += 512) {
        int d = i >> 5, s2 = 197 + (i & 31);
        if (s2 < 232) lds[VT_OFF + d * 232 + s2] = 0;
    }
    __syncthreads();

    // projection
    for (int st = w; st < 13; st += 8) {
        bf16x8 a0 = *(const bf16x8*)(lds + RG_OFF + (st * 16 + lr) * 72 + lk4 * 8);
        bf16x8 a1 = *(const bf16x8*)(lds + RG_OFF + (st * 16 + lr) * 72 + 32 + lk4 * 8);
#pragma unroll
        for (int tt = 0; tt < 3; tt++) {
            if (QTMAX == 1 && tt == 0 && st >= QTMAX) continue;
            const float* bias = (tt == 0) ? bq : (tt == 1) ? bk : bv;
            __builtin_amdgcn_s_setprio(1);
            f32x4 pacc[4];
#pragma unroll
            for (int et = 0; et < 4; et++) {
                int wrow = (tt * 64 + et * 16 + lr) * 72;
                bf16x8 b0 = *(const bf16x8*)(lds + WS_OFF + wrow + lk4 * 8);
                bf16x8 b1 = *(const bf16x8*)(lds + WS_OFF + wrow + 32 + lk4 * 8);
                f32x4 acc = {0.f, 0.f, 0.f, 0.f};
                acc = mfma16(a0, b0, acc);
                acc = mfma16(a1, b1, acc);
                pacc[et] = acc;
            }
            __builtin_amdgcn_s_setprio(0);
#pragma unroll
            for (int et = 0; et < 4; et++) {
                int e = et * 16 + lr;
                float bval = bias[hd * 64 + e];
#pragma unroll
                for (int r = 0; r < 4; r++) {
                    int s = st * 16 + lk4 * 4 + r;
                    if (s < SEQ) {
                        unsigned short val = f2bf(pacc[et][r] + bval);
                        if (tt == 0) lds[QS_OFF + s * 72 + e] = val;
                        else if (tt == 1) lds[KS_OFF + s * 72 + e] = val;
                        else lds[VT_OFF + e * 232 + s] = val;
                    }
                }
            }
        }
    }
    __syncthreads();

    const int Pb = RG_OFF + w * 3712;
    {
        int jj = 208 + lk4 * 4;
        lds[Pb + lr * 232 + jj + 0] = 0;
        lds[Pb + lr * 232 + jj + 1] = 0;
        lds[Pb + lr * 232 + jj + 2] = 0;
        lds[Pb + lr * 232 + jj + 3] = 0;
    }

    // attention: wave w handles q-tiles w and w+8 with shared K reads
    const int qt0 = w, qt1 = w + 8;
    if (qt0 < QTMAX) {
        const int qrow0 = min(qt0 * 16 + lr, SEQ - 1);
        bf16x8 q00 = *(const bf16x8*)(lds + QS_OFF + qrow0 * 72 + lk4 * 8);
        bf16x8 q01 = *(const bf16x8*)(lds + QS_OFF + qrow0 * 72 + 32 + lk4 * 8);
        f32x4 st0[13];
#pragma unroll
        for (int jt = 0; jt < 13; jt++) st0[jt] = (f32x4){0.f, 0.f, 0.f, 0.f};
        if (qt1 < QTMAX) {
            const int qrow1 = min(qt1 * 16 + lr, SEQ - 1);
            bf16x8 q10 = *(const bf16x8*)(lds + QS_OFF + qrow1 * 72 + lk4 * 8);
            bf16x8 q11 = *(const bf16x8*)(lds + QS_OFF + qrow1 * 72 + 32 + lk4 * 8);
            f32x4 st1[13];
#pragma unroll
            for (int jt = 0; jt < 13; jt++) st1[jt] = (f32x4){0.f, 0.f, 0.f, 0.f};
            __builtin_amdgcn_s_setprio(1);
#pragma unroll
            for (int jt = 0; jt < 13; jt++) {
                int jrow = min(jt * 16 + lr, SEQ - 1);
                bf16x8 k0 = *(const bf16x8*)(lds + KS_OFF + jrow * 72 + lk4 * 8);
                bf16x8 k1 = *(const bf16x8*)(lds + KS_OFF + jrow * 72 + 32 + lk4 * 8);
                st0[jt] = mfma16(k0, q00, st0[jt]);
                st0[jt] = mfma16(k1, q01, st0[jt]);
                st1[jt] = mfma16(k0, q10, st1[jt]);
                st1[jt] = mfma16(k1, q11, st1[jt]);
            }
            __builtin_amdgcn_s_setprio(0);
            SOFTMAX_PV(st0, qt0);
            SOFTMAX_PV(st1, qt1);
        } else {
            __builtin_amdgcn_s_setprio(1);
#pragma unroll
            for (int jt = 0; jt < 13; jt++) {
                int jrow = min(jt * 16 + lr, SEQ - 1);
                bf16x8 k0 = *(const bf16x8*)(lds + KS_OFF + jrow * 72 + lk4 * 8);
                bf16x8 k1 = *(const bf16x8*)(lds + KS_OFF + jrow * 72 + 32 + lk4 * 8);
                st0[jt] = mfma16(k0, q00, st0[jt]);
                st0[jt] = mfma16(k1, q01, st0[jt]);
            }
            __builtin_amdgcn_s_setprio(0);
            SOFTMAX_PV(st0, qt0);
        }
    }
}

// ---------------- bf16 MFMA NT GEMM, 128x128 tile, counted-vmcnt dbuf ----------------
// MODE 1: gelu(acc+bias) -> bf16 C ; MODE 2: acc+bias+res -> fp32 C
template <int MODE, int SWAPXY>
__global__ __launch_bounds__(256) void gemm_bf(const unsigned short* __restrict__ A,
                                               const unsigned short* __restrict__ Bw,
                                               const float* __restrict__ bias,
                                               void* __restrict__ Cout,
                                               const float* __restrict__ res,
                                               int M, int N, int K) {
    __shared__ __align__(16) unsigned short As[2][128 * 32];
    __shared__ __align__(16) unsigned short Bs[2][128 * 32];
    const int t = threadIdx.x, l = t & 63, w = t >> 6;
    const int bm = (SWAPXY ? blockIdx.y : blockIdx.x) * 128;
    const int bn = (SWAPXY ? blockIdx.x : blockIdx.y) * 128;
    const int wr = w >> 1, wc = w & 1;
    f32x4 acc[4][4] = {};

    const int ra0 = t >> 2, ka0 = (t & 3) * 8;
    const int ra1 = (t + 256) >> 2, ka1 = ((t + 256) & 3) * 8;
    const unsigned short* Ar0 = A + (size_t)min(bm + ra0, M - 1) * K + ka0;
    const unsigned short* Ar1 = A + (size_t)min(bm + ra1, M - 1) * K + ka1;
    const unsigned short* Br0 = Bw + (size_t)(bn + ra0) * K + ka0;
    const unsigned short* Br1 = Bw + (size_t)(bn + ra1) * K + ka1;
    const int lo0 = (0 * 256 + w * 64) * 8, lo1 = (1 * 256 + w * 64) * 8;
    const int lr = l & 15, lk = (l >> 4) * 8;

    gload_lds16(Ar0, As[0] + lo0);
    gload_lds16(Ar1, As[0] + lo1);
    gload_lds16(Br0, Bs[0] + lo0);
    gload_lds16(Br1, Bs[0] + lo1);
    int cur = 0;
    for (int k0 = 0; k0 < K; k0 += 32) {
        if (k0 + 32 < K) {
            gload_lds16(Ar0 + k0 + 32, As[cur ^ 1] + lo0);
            gload_lds16(Ar1 + k0 + 32, As[cur ^ 1] + lo1);
            gload_lds16(Br0 + k0 + 32, Bs[cur ^ 1] + lo0);
            gload_lds16(Br1 + k0 + 32, Bs[cur ^ 1] + lo1);
            WAIT_VMCNT_4();
        } else {
            WAIT_VMCNT_0();
        }
        BARRIER_RAW();
        bf16x8 a[4], bfr[4];
#pragma unroll
        for (int m = 0; m < 4; m++)
            a[m] = *(const bf16x8*)(As[cur] + (wr * 64 + m * 16 + lr) * 32 + lk);
#pragma unroll
        for (int n = 0; n < 4; n++)
            bfr[n] = *(const bf16x8*)(Bs[cur] + (wc * 64 + n * 16 + lr) * 32 + lk);
#pragma unroll
        for (int m = 0; m < 4; m++)
#pragma unroll
            for (int n = 0; n < 4; n++)
                acc[m][n] = mfma16(a[m], bfr[n], acc[m][n]);
        BARRIER_RAW();
        cur ^= 1;
    }

#pragma unroll
    for (int m = 0; m < 4; m++) {
#pragma unroll
        for (int r = 0; r < 4; r++) {
            int gm = bm + wr * 64 + m * 16 + (l >> 4) * 4 + r;
            if (gm >= M) continue;
#pragma unroll
            for (int n = 0; n < 4; n++) {
                int gn = bn + wc * 64 + n * 16 + lr;
                float vb = acc[m][n][r] + bias[gn];
                if (MODE == 1) {
                    float gl = 0.5f * vb * (1.0f + erff(vb * 0.70710678118f));
                    ((unsigned short*)Cout)[(size_t)gm * N + gn] = f2bf(gl);
                } else {
                    ((float*)Cout)[(size_t)gm * N + gn] = vb + res[(size_t)gm * N + gn];
                }
            }
        }
    }
}

// ---------------- split-K NT GEMM: partials[z][m][n], K chunk = KFULL/SPLITK ----------------
__global__ __launch_bounds__(256) void gemm_splitk(const unsigned short* __restrict__ A,
                                                   const unsigned short* __restrict__ Bw,
                                                   float* __restrict__ parts,
                                                   int M, int N, int KFULL) {
    __shared__ __align__(16) unsigned short As[2][128 * 32];
    __shared__ __align__(16) unsigned short Bs[2][128 * 32];
    const int t = threadIdx.x, l = t & 63, w = t >> 6;
    const int bm = blockIdx.x * 128, bn = blockIdx.y * 128;
    const int KC = KFULL / SPLITK;
    const int kbeg = blockIdx.z * KC;
    const int wr = w >> 1, wc = w & 1;
    f32x4 acc[4][4] = {};

    const int ra0 = t >> 2, ka0 = (t & 3) * 8;
    const int ra1 = (t + 256) >> 2, ka1 = ((t + 256) & 3) * 8;
    const unsigned short* Ar0 = A + (size_t)min(bm + ra0, M - 1) * KFULL + kbeg + ka0;
    const unsigned short* Ar1 = A + (size_t)min(bm + ra1, M - 1) * KFULL + kbeg + ka1;
    const unsigned short* Br0 = Bw + (size_t)(bn + ra0) * KFULL + kbeg + ka0;
    const unsigned short* Br1 = Bw + (size_t)(bn + ra1) * KFULL + kbeg + ka1;
    const int lo0 = (0 * 256 + w * 64) * 8, lo1 = (1 * 256 + w * 64) * 8;
    const int lr = l & 15, lk = (l >> 4) * 8;

    gload_lds16(Ar0, As[0] + lo0);
    gload_lds16(Ar1, As[0] + lo1);
    gload_lds16(Br0, Bs[0] + lo0);
    gload_lds16(Br1, Bs[0] + lo1);
    int cur = 0;
    for (int k0 = 0; k0 < KC; k0 += 32) {
        if (k0 + 32 < KC) {
            gload_lds16(Ar0 + k0 + 32, As[cur ^ 1] + lo0);
            gload_lds16(Ar1 + k0 + 32, As[cur ^ 1] + lo1);
            gload_lds16(Br0 + k0 + 32, Bs[cur ^ 1] + lo0);
            gload_lds16(Br1 + k0 + 32, Bs[cur ^ 1] + lo1);
            WAIT_VMCNT_4();
        } else {
            WAIT_VMCNT_0();
        }
        BARRIER_RAW();
        bf16x8 a[4], bfr[4];
#pragma unroll
        for (int m = 0; m < 4; m++)
            a[m] = *(const bf16x8*)(As[cur] + (wr * 64 + m * 16 + lr) * 32 + lk);
#pragma unroll
        for (int n = 0; n < 4; n++)
            bfr[n] = *(const bf16x8*)(Bs[cur] + (wc * 64 + n * 16 + lr) * 32 + lk);
#pragma unroll
        for (int m = 0; m < 4; m++)
#pragma unroll
            for (int n = 0; n < 4; n++)
                acc[m][n] = mfma16(a[m], bfr[n], acc[m][n]);
        BARRIER_RAW();
        cur ^= 1;
    }

    float* po = parts + (size_t)blockIdx.z * M * N;
#pragma unroll
    for (int m = 0; m < 4; m++) {
#pragma unroll
        for (int r = 0; r < 4; r++) {
            int gm = bm + wr * 64 + m * 16 + (l >> 4) * 4 + r;
            if (gm >= M) continue;
#pragma unroll
            for (int n = 0; n < 4; n++) {
                int gn = bn + wc * 64 + n * 16 + lr;
                po[(size_t)gm * N + gn] = acc[m][n][r];
            }
        }
    }
}

// ---------------- classifier head (folds last-layer split-K partials + b2) ----------------
__global__ __launch_bounds__(256) void head_kernel(const float* __restrict__ x,
                                                   const float* __restrict__ Wh,
                                                   const float* __restrict__ bh,
                                                   float* __restrict__ logits,
                                                   const float* __restrict__ cparts,
                                                   const float* __restrict__ b2l) {
    __shared__ float xs[768];
    int b = blockIdx.x;
    int tid = threadIdx.x;
#pragma unroll
    for (int i = 0; i < 3; i++) {
        int c = tid + i * 256;
        float v = x[(size_t)b * SEQ * DIM + c];
        if (cparts) {
            v += b2l[c];
#pragma unroll
            for (int kc = 0; kc < SPLITK; kc++)
                v += cparts[((size_t)kc * NBATCH + b) * DIM + c];
        }
        xs[c] = v;
    }
    __syncthreads();
    int wave = tid >> 6, lane = tid & 63;
    int o = blockIdx.y * 4 + wave;
    if (o < NOUT) {
        float acc = 0;
#pragma unroll
        for (int t = 0; t < 12; t++) {
            int d = lane + t * 64;
            acc = fmaf(xs[d], Wh[(size_t)o * DIM + d], acc);
        }
#pragma unroll
        for (int off = 32; off > 0; off >>= 1) acc += __shfl_down(acc, off, 64);
        if (lane == 0) logits[b * NOUT + o] = acc + bh[o];
    }
}

__global__ __launch_bounds__(256) void softmax_kernel(const float* __restrict__ logits,
                                                      float* __restrict__ out) {
    __shared__ float tmp[4];
    int b = blockIdx.x, tid = threadIdx.x;
    float vals[4];
    float mx = -1e30f;
#pragma unroll
    for (int i = 0; i < 4; i++) {
        int c = tid + i * 256;
        vals[i] = (c < NOUT) ? logits[b * NOUT + c] : -1e30f;
        mx = fmaxf(mx, vals[i]);
    }
#pragma unroll
    for (int o = 32; o > 0; o >>= 1) mx = fmaxf(mx, __shfl_down(mx, o, 64));
    int wave = tid >> 6, lane = tid & 63;
    __syncthreads();
    if (lane == 0) tmp[wave] = mx;
    __syncthreads();
    mx = fmaxf(fmaxf(tmp[0], tmp[1]), fmaxf(tmp[2], tmp[3]));
    float s = 0;
#pragma unroll
    for (int i = 0; i < 4; i++) {
        int c = tid + i * 256;
        if (c < NOUT) {
            vals[i] = __expf(vals[i] - mx);
            s += vals[i];
        } else vals[i] = 0.f;
    }
#pragma unroll
    for (int o = 32; o > 0; o >>= 1) s += __shfl_down(s, o, 64);
    __syncthreads();
    if (lane == 0) tmp[wave] = s;
    __syncthreads();
    s = tmp[0] + tmp[1] + tmp[2] + tmp[3];
    float invs = 1.0f / s;
#pragma unroll
    for (int i = 0; i < 4; i++) {
        int c = tid + i * 256;
        if (c < NOUT) out[b * NOUT + c] = vals[i] * invs;
    }
}

extern "C" void kernel_launch(void* const* d_in, const int* in_sizes, int n_in,
                              void* d_out, int out_size, void* d_ws, size_t ws_size,
                              hipStream_t stream) {
    const float* images = (const float*)d_in[0];
    const float* Wp   = (const float*)d_in[1];
    const float* bp   = (const float*)d_in[2];
    const float* cls  = (const float*)d_in[3];
    const float* pos  = (const float*)d_in[4];
    const float* ln1g = (const float*)d_in[5];
    const float* ln1b = (const float*)d_in[6];
    const float* Wq   = (const float*)d_in[7];
    const float* bq   = (const float*)d_in[8];
    const float* Wk   = (const float*)d_in[9];
    const float* bk   = (const float*)d_in[10];
    const float* Wv   = (const float*)d_in[11];
    const float* bv   = (const float*)d_in[12];
    const float* ln2g = (const float*)d_in[13];
    const float* ln2b = (const float*)d_in[14];
    const float* W1   = (const float*)d_in[15];
    const float* b1   = (const float*)d_in[16];
    const float* W2   = (const float*)d_in[17];
    const float* b2   = (const float*)d_in[18];
    const float* Wh   = (const float*)d_in[19];
    const float* bh   = (const float*)d_in[20];
    float* out = (float*)d_out;

    const size_t NX = (size_t)MROWS * DIM;              // 4,841,472
    const size_t NIMG = (size_t)NBATCH * 3 * 224 * 224; // 4,816,896
    const size_t NW = (size_t)MDIM * DIM;               // 2,359,296 per layer

    char* p = (char*)d_ws;
    float* x      = (float*)p;            p += NX * 4;
    float* h      = (float*)p;            p += NX * 4;
    float* logits = (float*)p;            p += (size_t)NBATCH * NOUT * 4;
    unsigned short* hbf   = (unsigned short*)p; p += NX * 2;
    unsigned short* h2bf  = (unsigned short*)p; p += NX * 2;
    unsigned short* mid   = (unsigned short*)p; p += (size_t)MROWS * MDIM * 2;
    unsigned short* wqkvb = (unsigned short*)p; p += (size_t)NLAYER * NHEAD * 12288 * 2;
    unsigned short* imgbf = (unsigned short*)p; p += NIMG * 2;
    unsigned short* wpbf  = (unsigned short*)p; p += (size_t)DIM * DIM * 2;

    size_t used = (size_t)(p - (char*)d_ws);
    bool skq = ws_size >= used + (size_t)SPLITK * NX * 4;
    float* parts = (float*)p;
    if (skq) p += (size_t)SPLITK * NX * 4;
    used = (size_t)(p - (char*)d_ws);
    bool big = ws_size >= used + (size_t)2 * NLAYER * NW * 2;
    unsigned short* w1a = (unsigned short*)p;
    unsigned short* w2a = big ? w1a + (size_t)NLAYER * NW : w1a + NW;

    cls_pos_kernel<<<dim3(NBATCH), dim3(256), 0, stream>>>(cls, pos, x);
    cvt4<<<dim3(2048), dim3(256), 0, stream>>>(images, imgbf, (int)(NIMG / 4));
    cvt4<<<dim3(576), dim3(256), 0, stream>>>(Wp, wpbf, (int)(DIM * DIM / 4));
    cvt_qkvw<<<dim3(1024), dim3(256), 0, stream>>>(Wq, Wk, Wv, wqkvb);
    gemm_patch_bf<<<dim3(49, 6), dim3(256), 0, stream>>>(imgbf, wpbf, bp, pos, x);
    if (big) {
        cvt4<<<dim3(2048), dim3(256), 0, stream>>>(W1, w1a, (int)(NLAYER * NW / 4));
        cvt4<<<dim3(2048), dim3(256), 0, stream>>>(W2, w2a, (int)(NLAYER * NW / 4));
    }

    for (int l = 0; l < NLAYER; l++) {
        const unsigned short* wl1 = big ? w1a + (size_t)l * NW : w1a;
        const unsigned short* wl2 = big ? w2a + (size_t)l * NW : w2a;
        if (!big) {
            cvt4<<<dim3(2048), dim3(256), 0, stream>>>(W1 + (size_t)l * NW, w1a, (int)(NW / 4));
            cvt4<<<dim3(2048), dim3(256), 0, stream>>>(W2 + (size_t)l * NW, w1a + NW, (int)(NW / 4));
        }
        if (skq && l > 0) {
            ln_wave<0, 1><<<dim3(MROWS / 4), dim3(256), 0, stream>>>(
                x, nullptr, x, hbf, ln1g + l * DIM, ln1b + l * DIM, parts, b2 + (l - 1) * DIM, 1);
        } else {
            ln_wave<0, 0><<<dim3(MROWS / 4), dim3(256), 0, stream>>>(
                x, nullptr, nullptr, hbf, ln1g + l * DIM, ln1b + l * DIM, nullptr, nullptr, 1);
        }
        bool last = skq && (l == NLAYER - 1);
        if (last) {
            fused_attn<1><<<dim3(NBATCH, NHEAD), dim3(512), 0, stream>>>(
                hbf, wqkvb + (size_t)l * NHEAD * 12288,
                bq + l * NHEAD * DH, bk + l * NHEAD * DH, bv + l * NHEAD * DH, h);
            ln_wave<1, 0><<<dim3(NBATCH / 4), dim3(256), 0, stream>>>(
                x, h, x, h2bf, ln2g + l * DIM, ln2b + l * DIM, nullptr, nullptr, SEQ);
            gemm_bf<1, 1><<<dim3(24, 1), dim3(256), 0, stream>>>(
                h2bf, wl1, b1 + l * MDIM, mid, nullptr, NBATCH, MDIM, DIM);
            gemm_splitk<<<dim3(1, 6, SPLITK), dim3(256), 0, stream>>>(
                mid, wl2, parts, NBATCH, DIM, MDIM);
        } else {
            fused_attn<13><<<dim3(NBATCH, NHEAD), dim3(512), 0, stream>>>(
                hbf, wqkvb + (size_t)l * NHEAD * 12288,
                bq + l * NHEAD * DH, bk + l * NHEAD * DH, bv + l * NHEAD * DH, h);
            ln_wave<1, 0><<<dim3(MROWS / 4), dim3(256), 0, stream>>>(
                x, h, x, h2bf, ln2g + l * DIM, ln2b + l * DIM, nullptr, nullptr, 1);
            gemm_bf<1, 1><<<dim3(24, 50), dim3(256), 0, stream>>>(
                h2bf, wl1, b1 + l * MDIM, mid, nullptr, MROWS, MDIM, DIM);
            if (skq) {
                gemm_splitk<<<dim3(50, 6, SPLITK), dim3(256), 0, stream>>>(
                    mid, wl2, parts, MROWS, DIM, MDIM);
            } else {
                gemm_bf<2, 0><<<dim3(50, 6), dim3(256), 0, stream>>>(
                    mid, wl2, b2 + l * DIM, x, x, MROWS, DIM, MDIM);
            }
        }
    }

    head_kernel<<<dim3(NBATCH, 250), dim3(256), 0, stream>>>(
        x, Wh, bh, logits,
        skq ? parts : nullptr, skq ? b2 + (NLAYER - 1) * DIM : nullptr);
    softmax_kernel<<<dim3(NBATCH), dim3(256), 0, stream>>>(logits, out);
}

// Round 14
// 2133.487 us; speedup vs baseline: 1.3793x; 1.0061x over previous
//
#include <hip/hip_runtime.h>
#include <math.h>
#include <stdint.h>

#define NBATCH 32
#define SEQ 197
#define DIM 768
#define NHEAD 12
#define DH 64
#define MDIM 3072
#define NLAYER 12
#define NPATCH 196
#define NOUT 1000
#define MROWS (NBATCH * SEQ)   // 6304
#define SPLITK 2

typedef __bf16 bf16x8 __attribute__((ext_vector_type(8)));
typedef float f32x4 __attribute__((ext_vector_type(4)));

__device__ __forceinline__ unsigned short f2bf(float f) {
    unsigned u = __float_as_uint(f);
    unsigned r = u + 0x7fffu + ((u >> 16) & 1u);
    return (unsigned short)(r >> 16);
}

__device__ __forceinline__ float bf2f(unsigned short u) {
    return __uint_as_float((unsigned)u << 16);
}

__device__ __forceinline__ f32x4 mfma16(bf16x8 a, bf16x8 b, f32x4 c) {
    return __builtin_amdgcn_mfma_f32_16x16x32_bf16(a, b, c, 0, 0, 0);
}

// async global->LDS 16B: lds pointer wave-uniform base; HW writes lane l at base + l*16.
__device__ __forceinline__ void gload_lds16(const void* g, const void* lds) {
    __builtin_amdgcn_global_load_lds(
        (const __attribute__((address_space(1))) void*)(uintptr_t)g,
        (__attribute__((address_space(3))) void*)(uint32_t)(uintptr_t)lds,
        16, 0, 0);
}

#define WAIT_VMCNT_4() asm volatile("s_waitcnt vmcnt(4)" ::: "memory")
#define WAIT_VMCNT_0() asm volatile("s_waitcnt vmcnt(0)" ::: "memory")
#define BARRIER_RAW()                      \
    do {                                   \
        asm volatile("" ::: "memory");     \
        __builtin_amdgcn_s_barrier();      \
        asm volatile("" ::: "memory");     \
    } while (0)

// ---------------- fp32 -> bf16 converter (grid-stride) ----------------
__global__ __launch_bounds__(256) void cvt4(const float* __restrict__ src,
                                            unsigned short* __restrict__ dst, int n4) {
    int stride = gridDim.x * 256;
    for (int i = blockIdx.x * 256 + threadIdx.x; i < n4; i += stride) {
        float4 f = *(const float4*)(src + (size_t)i * 4);
        ushort4 o;
        o.x = f2bf(f.x); o.y = f2bf(f.y); o.z = f2bf(f.z); o.w = f2bf(f.w);
        *(ushort4*)(dst + (size_t)i * 4) = o;
    }
}

// gather Wq/Wk/Wv [L][H][e][d] -> wqkvb [L][H][3*64 rows][64] bf16
__global__ __launch_bounds__(256) void cvt_qkvw(const float* __restrict__ Wq,
                                                const float* __restrict__ Wk,
                                                const float* __restrict__ Wv,
                                                unsigned short* __restrict__ dst) {
    const int n = NLAYER * NHEAD * 3 * 64 * 64;
    int stride = gridDim.x * 256;
    for (int i = blockIdx.x * 256 + threadIdx.x; i < n; i += stride) {
        int d = i & 63, e = (i >> 6) & 63;
        int v = i >> 12;
        int t = v % 3, hh = (v / 3) % NHEAD, l = v / (3 * NHEAD);
        const float* src = (t == 0) ? Wq : (t == 1) ? Wk : Wv;
        dst[i] = f2bf(src[(((size_t)(l * NHEAD + hh)) * 64 + e) * 64 + d]);
    }
}

// ---------------- cls + pos init ----------------
__global__ __launch_bounds__(256) void cls_pos_kernel(const float* __restrict__ cls,
                                                      const float* __restrict__ pos,
                                                      float* __restrict__ x) {
    int b = blockIdx.x, tid = threadIdx.x;
#pragma unroll
    for (int i = 0; i < 3; i++) {
        int c = tid + i * 256;
        x[(size_t)b * SEQ * DIM + c] = cls[c] + pos[c];
    }
}

// ---------------- patch-embed GEMM: bf16 MFMA, gathered A, counted-vmcnt dbuf ----------------
__global__ __launch_bounds__(256) void gemm_patch_bf(const unsigned short* __restrict__ imgbf,
                                                     const unsigned short* __restrict__ wpbf,
                                                     const float* __restrict__ bp,
                                                     const float* __restrict__ pos,
                                                     float* __restrict__ x) {
    __shared__ __align__(16) unsigned short As[2][128 * 32];
    __shared__ __align__(16) unsigned short Bs[2][128 * 32];
    const int t = threadIdx.x, l = t & 63, w = t >> 6;
    const int bm = blockIdx.x * 128, bn = blockIdx.y * 128;
    const int wr = w >> 1, wc = w & 1;
    f32x4 acc[4][4] = {};

    const int ra0 = t >> 2, ka0 = (t & 3) * 8;
    const int ra1 = (t + 256) >> 2, ka1 = ((t + 256) & 3) * 8;
    int gm0 = bm + ra0, b0 = gm0 / NPATCH, p0 = gm0 % NPATCH;
    int gm1 = bm + ra1, b1 = gm1 / NPATCH, p1 = gm1 % NPATCH;
    const unsigned short* ib0 =
        imgbf + ((size_t)b0 * 3 * 224 + (size_t)(p0 / 14) * 16) * 224 + (p0 % 14) * 16;
    const unsigned short* ib1 =
        imgbf + ((size_t)b1 * 3 * 224 + (size_t)(p1 / 14) * 16) * 224 + (p1 % 14) * 16;
    const unsigned short* Br0 = wpbf + (size_t)(bn + ra0) * 768 + ka0;
    const unsigned short* Br1 = wpbf + (size_t)(bn + ra1) * 768 + ka1;
    const int lA0 = (0 * 256 + w * 64) * 8, lA1 = (1 * 256 + w * 64) * 8;
    const int lr = l & 15, lk = (l >> 4) * 8;

#define PATCH_STAGE(buf, k0)                                                   \
    {                                                                          \
        int kA0 = (k0) + ka0, kA1 = (k0) + ka1;                                \
        int c0 = kA0 >> 8, i0 = (kA0 >> 4) & 15, j0 = kA0 & 15;                \
        int c1 = kA1 >> 8, i1 = (kA1 >> 4) & 15, j1 = kA1 & 15;                \
        gload_lds16(ib0 + ((size_t)c0 * 224 + i0) * 224 + j0, As[buf] + lA0);  \
        gload_lds16(ib1 + ((size_t)c1 * 224 + i1) * 224 + j1, As[buf] + lA1);  \
        gload_lds16(Br0 + (k0), Bs[buf] + lA0);                                \
        gload_lds16(Br1 + (k0), Bs[buf] + lA1);                                \
    }

    PATCH_STAGE(0, 0);
    int cur = 0;
    for (int k0 = 0; k0 < 768; k0 += 32) {
        if (k0 + 32 < 768) {
            PATCH_STAGE(cur ^ 1, k0 + 32);
            WAIT_VMCNT_4();
        } else {
            WAIT_VMCNT_0();
        }
        BARRIER_RAW();
        bf16x8 a[4], bfr[4];
#pragma unroll
        for (int m = 0; m < 4; m++)
            a[m] = *(const bf16x8*)(As[cur] + (wr * 64 + m * 16 + lr) * 32 + lk);
#pragma unroll
        for (int n = 0; n < 4; n++)
            bfr[n] = *(const bf16x8*)(Bs[cur] + (wc * 64 + n * 16 + lr) * 32 + lk);
#pragma unroll
        for (int m = 0; m < 4; m++)
#pragma unroll
            for (int n = 0; n < 4; n++)
                acc[m][n] = mfma16(a[m], bfr[n], acc[m][n]);
        BARRIER_RAW();
        cur ^= 1;
    }
#undef PATCH_STAGE

#pragma unroll
    for (int m = 0; m < 4; m++) {
#pragma unroll
        for (int r = 0; r < 4; r++) {
            int gm = bm + wr * 64 + m * 16 + (l >> 4) * 4 + r;
            int b2 = gm / NPATCH, p2 = gm % NPATCH;
            size_t orow = (size_t)(b2 * SEQ + 1 + p2) * DIM;
#pragma unroll
            for (int n = 0; n < 4; n++) {
                int gn = bn + wc * 64 + n * 16 + lr;
                x[orow + gn] = acc[m][n][r] + bp[gn] + pos[(size_t)(1 + p2) * DIM + gn];
            }
        }
    }
}

// ---------------- wave-per-row LayerNorm, bf16 h out ----------------
// addv (RES) is bf16. xmul: x rows strided (cls-only last layer).
template <int RES, int RED>
__global__ __launch_bounds__(256) void ln_wave(const float* __restrict__ x_in,
                                               const unsigned short* __restrict__ addv,
                                               float* __restrict__ x_out,
                                               unsigned short* __restrict__ h_out,
                                               const float* __restrict__ g,
                                               const float* __restrict__ bb,
                                               const float* __restrict__ parts,
                                               const float* __restrict__ badd,
                                               int xmul) {
    int w = threadIdx.x >> 6, l = threadIdx.x & 63;
    size_t row = (size_t)blockIdx.x * 4 + w;
    size_t xrow = row * xmul;
    const float* xr = x_in + xrow * DIM;
    float4 v[3];
    float s = 0.f;
#pragma unroll
    for (int u = 0; u < 3; u++) {
        int c = u * 256 + l * 4;
        v[u] = *(const float4*)(xr + c);
        if (RES) {
            ushort4 a4 = *(const ushort4*)(addv + xrow * DIM + c);
            v[u].x += bf2f(a4.x); v[u].y += bf2f(a4.y);
            v[u].z += bf2f(a4.z); v[u].w += bf2f(a4.w);
        }
        if (RED) {
            float4 b4 = *(const float4*)(badd + c);
            v[u].x += b4.x; v[u].y += b4.y; v[u].z += b4.z; v[u].w += b4.w;
#pragma unroll
            for (int kc = 0; kc < SPLITK; kc++) {
                float4 p4 = *(const float4*)(parts + ((size_t)kc * MROWS + row) * DIM + c);
                v[u].x += p4.x; v[u].y += p4.y; v[u].z += p4.z; v[u].w += p4.w;
            }
        }
        s += v[u].x + v[u].y + v[u].z + v[u].w;
    }
#pragma unroll
    for (int o = 1; o < 64; o <<= 1) s += __shfl_xor(s, o, 64);
    float mean = s * (1.0f / 768.0f);
    float s2 = 0.f;
#pragma unroll
    for (int u = 0; u < 3; u++) {
        float dx = v[u].x - mean, dy = v[u].y - mean, dz = v[u].z - mean, dw = v[u].w - mean;
        s2 += dx * dx + dy * dy + dz * dz + dw * dw;
    }
#pragma unroll
    for (int o = 1; o < 64; o <<= 1) s2 += __shfl_xor(s2, o, 64);
    float inv = rsqrtf(s2 * (1.0f / 768.0f) + 1e-5f);
#pragma unroll
    for (int u = 0; u < 3; u++) {
        int c = u * 256 + l * 4;
        float4 g4 = *(const float4*)(g + c);
        float4 b4 = *(const float4*)(bb + c);
        ushort4 o;
        o.x = f2bf((v[u].x - mean) * inv * g4.x + b4.x);
        o.y = f2bf((v[u].y - mean) * inv * g4.y + b4.y);
        o.z = f2bf((v[u].z - mean) * inv * g4.z + b4.z);
        o.w = f2bf((v[u].w - mean) * inv * g4.w + b4.w);
        *(ushort4*)(h_out + row * DIM + c) = o;
        if (RES || RED) *(float4*)(x_out + xrow * DIM + c) = v[u];
    }
}

// ================= fused QKV projection + attention (o written as bf16) =================
#define KS_OFF 0
#define QS_OFF 14400
#define VT_OFF 28800
#define RG_OFF 43648
#define WS_OFF (RG_OFF + 14400)

// softmax (in-register) + P->LDS + PV + O-write for one q-tile
#define SOFTMAX_PV(ST, QT)                                                              \
    do {                                                                                \
        float mx = -1e30f;                                                              \
        _Pragma("unroll") for (int jt = 0; jt < 13; jt++)                               \
            _Pragma("unroll") for (int r = 0; r < 4; r++) {                             \
                int j = jt * 16 + lk4 * 4 + r;                                          \
                float sv = ST[jt][r] * 0.125f;                                          \
                ST[jt][r] = (j < SEQ) ? sv : -1e30f;                                    \
                mx = fmaxf(mx, ST[jt][r]);                                              \
            }                                                                           \
        mx = fmaxf(mx, __shfl_xor(mx, 16, 64));                                         \
        mx = fmaxf(mx, __shfl_xor(mx, 32, 64));                                         \
        float sum = 0.f;                                                                \
        _Pragma("unroll") for (int jt = 0; jt < 13; jt++)                               \
            _Pragma("unroll") for (int r = 0; r < 4; r++) {                             \
                float pv_ = __expf(ST[jt][r] - mx);                                     \
                ST[jt][r] = pv_;                                                        \
                sum += pv_;                                                             \
            }                                                                           \
        sum += __shfl_xor(sum, 16, 64);                                                 \
        sum += __shfl_xor(sum, 32, 64);                                                 \
        float inv_ = 1.0f / sum;                                                        \
        _Pragma("unroll") for (int jt = 0; jt < 13; jt++) {                             \
            ushort4 pk;                                                                 \
            pk.x = f2bf(ST[jt][0] * inv_); pk.y = f2bf(ST[jt][1] * inv_);               \
            pk.z = f2bf(ST[jt][2] * inv_); pk.w = f2bf(ST[jt][3] * inv_);               \
            *(ushort4*)(lds + Pb + lr * 232 + jt * 16 + lk4 * 4) = pk;                  \
        }                                                                               \
        f32x4 oacc[4] = {};                                                             \
        __builtin_amdgcn_s_setprio(1);                                                  \
        _Pragma("unroll") for (int kt = 0; kt < 7; kt++) {                              \
            bf16x8 pa = *(const bf16x8*)(lds + Pb + lr * 232 + kt * 32 + lk4 * 8);      \
            _Pragma("unroll") for (int nt = 0; nt < 4; nt++) {                          \
                bf16x8 bv8 = *(const bf16x8*)(lds + VT_OFF + (nt * 16 + lr) * 232 +     \
                                              kt * 32 + lk4 * 8);                      \
                oacc[nt] = mfma16(pa, bv8, oacc[nt]);                                   \
            }                                                                           \
        }                                                                               \
        __builtin_amdgcn_s_setprio(0);                                                  \
        _Pragma("unroll") for (int nt = 0; nt < 4; nt++)                                \
            _Pragma("unroll") for (int r = 0; r < 4; r++) {                             \
                int qq = (QT) * 16 + lk4 * 4 + r;                                       \
                if (qq < SEQ)                                                           \
                    o[base + (size_t)qq * DIM + nt * 16 + lr] = f2bf(oacc[nt][r]);      \
            }                                                                           \
    } while (0)

template <int QTMAX>
__global__ __launch_bounds__(512) void fused_attn(const unsigned short* __restrict__ hbf,
                                                  const unsigned short* __restrict__ wqkv,
                                                  const float* __restrict__ bq,
                                                  const float* __restrict__ bk,
                                                  const float* __restrict__ bv,
                                                  unsigned short* __restrict__ o) {
    __shared__ __align__(16) unsigned short lds[73344];
    const int b = blockIdx.x, hd = blockIdx.y;
    const int t = threadIdx.x, l = t & 63, w = t >> 6;
    const size_t base = ((size_t)b * SEQ) * DIM + hd * DH;
    const int lr = l & 15, lk4 = l >> 4;
    const unsigned short* wh = wqkv + (size_t)hd * 12288;

    for (int i = t; i < 197 * 16; i += 512) {
        int s = i >> 4, c4 = i & 15;
        ushort4 v4 = *(const ushort4*)(hbf + base + (size_t)s * DIM + c4 * 4);
        *(ushort4*)(lds + RG_OFF + s * 72 + c4 * 4) = v4;
    }
    if (t < 48) {
        int s = 197 + (t >> 4), c4 = t & 15;
        ushort4 z; z.x = 0; z.y = 0; z.z = 0; z.w = 0;
        *(ushort4*)(lds + RG_OFF + s * 72 + c4 * 4) = z;
    }
    for (int i = t; i < 192 * 16; i += 512) {
        int r = i >> 4, c4 = i & 15;
        ushort4 v4 = *(const ushort4*)(wh + (size_t)r * 64 + c4 * 4);
        *(ushort4*)(lds + WS_OFF + r * 72 + c4 * 4) = v4;
    }
    for (int i = t; i < 64 * 32; i += 512) {
        int d = i >> 5, s2 = 197 + (i & 31);
        if (s2 < 232) lds[VT_OFF + d * 232 + s2] = 0;
    }
    __syncthreads();

    // projection
    for (int st = w; st < 13; st += 8) {
        bf16x8 a0 = *(const bf16x8*)(lds + RG_OFF + (st * 16 + lr) * 72 + lk4 * 8);
        bf16x8 a1 = *(const bf16x8*)(lds + RG_OFF + (st * 16 + lr) * 72 + 32 + lk4 * 8);
#pragma unroll
        for (int tt = 0; tt < 3; tt++) {
            if (QTMAX == 1 && tt == 0 && st >= QTMAX) continue;
            const float* bias = (tt == 0) ? bq : (tt == 1) ? bk : bv;
            __builtin_amdgcn_s_setprio(1);
            f32x4 pacc[4];
#pragma unroll
            for (int et = 0; et < 4; et++) {
                int wrow = (tt * 64 + et * 16 + lr) * 72;
                bf16x8 b0 = *(const bf16x8*)(lds + WS_OFF + wrow + lk4 * 8);
                bf16x8 b1 = *(const bf16x8*)(lds + WS_OFF + wrow + 32 + lk4 * 8);
                f32x4 acc = {0.f, 0.f, 0.f, 0.f};
                acc = mfma16(a0, b0, acc);
                acc = mfma16(a1, b1, acc);
                pacc[et] = acc;
            }
            __builtin_amdgcn_s_setprio(0);
#pragma unroll
            for (int et = 0; et < 4; et++) {
                int e = et * 16 + lr;
                float bval = bias[hd * 64 + e];
#pragma unroll
                for (int r = 0; r < 4; r++) {
                    int s = st * 16 + lk4 * 4 + r;
                    if (s < SEQ) {
                        unsigned short val = f2bf(pacc[et][r] + bval);
                        if (tt == 0) lds[QS_OFF + s * 72 + e] = val;
                        else if (tt == 1) lds[KS_OFF + s * 72 + e] = val;
                        else lds[VT_OFF + e * 232 + s] = val;
                    }
                }
            }
        }
    }
    __syncthreads();

    const int Pb = RG_OFF + w * 3712;
    {
        int jj = 208 + lk4 * 4;
        lds[Pb + lr * 232 + jj + 0] = 0;
        lds[Pb + lr * 232 + jj + 1] = 0;
        lds[Pb + lr * 232 + jj + 2] = 0;
        lds[Pb + lr * 232 + jj + 3] = 0;
    }

    // attention: wave w handles q-tiles w and w+8 with shared K reads
    const int qt0 = w, qt1 = w + 8;
    if (qt0 < QTMAX) {
        const int qrow0 = min(qt0 * 16 + lr, SEQ - 1);
        bf16x8 q00 = *(const bf16x8*)(lds + QS_OFF + qrow0 * 72 + lk4 * 8);
        bf16x8 q01 = *(const bf16x8*)(lds + QS_OFF + qrow0 * 72 + 32 + lk4 * 8);
        f32x4 st0[13];
#pragma unroll
        for (int jt = 0; jt < 13; jt++) st0[jt] = (f32x4){0.f, 0.f, 0.f, 0.f};
        if (qt1 < QTMAX) {
            const int qrow1 = min(qt1 * 16 + lr, SEQ - 1);
            bf16x8 q10 = *(const bf16x8*)(lds + QS_OFF + qrow1 * 72 + lk4 * 8);
            bf16x8 q11 = *(const bf16x8*)(lds + QS_OFF + qrow1 * 72 + 32 + lk4 * 8);
            f32x4 st1[13];
#pragma unroll
            for (int jt = 0; jt < 13; jt++) st1[jt] = (f32x4){0.f, 0.f, 0.f, 0.f};
            __builtin_amdgcn_s_setprio(1);
#pragma unroll
            for (int jt = 0; jt < 13; jt++) {
                int jrow = min(jt * 16 + lr, SEQ - 1);
                bf16x8 k0 = *(const bf16x8*)(lds + KS_OFF + jrow * 72 + lk4 * 8);
                bf16x8 k1 = *(const bf16x8*)(lds + KS_OFF + jrow * 72 + 32 + lk4 * 8);
                st0[jt] = mfma16(k0, q00, st0[jt]);
                st0[jt] = mfma16(k1, q01, st0[jt]);
                st1[jt] = mfma16(k0, q10, st1[jt]);
                st1[jt] = mfma16(k1, q11, st1[jt]);
            }
            __builtin_amdgcn_s_setprio(0);
            SOFTMAX_PV(st0, qt0);
            SOFTMAX_PV(st1, qt1);
        } else {
            __builtin_amdgcn_s_setprio(1);
#pragma unroll
            for (int jt = 0; jt < 13; jt++) {
                int jrow = min(jt * 16 + lr, SEQ - 1);
                bf16x8 k0 = *(const bf16x8*)(lds + KS_OFF + jrow * 72 + lk4 * 8);
                bf16x8 k1 = *(const bf16x8*)(lds + KS_OFF + jrow * 72 + 32 + lk4 * 8);
                st0[jt] = mfma16(k0, q00, st0[jt]);
                st0[jt] = mfma16(k1, q01, st0[jt]);
            }
            __builtin_amdgcn_s_setprio(0);
            SOFTMAX_PV(st0, qt0);
        }
    }
}

// ---------------- bf16 MFMA NT GEMM, 128x128 tile, counted-vmcnt dbuf ----------------
// MODE 1: gelu(acc+bias) -> bf16 C ; MODE 2: acc+bias+res -> fp32 C
template <int MODE, int SWAPXY>
__global__ __launch_bounds__(256) void gemm_bf(const unsigned short* __restrict__ A,
                                               const unsigned short* __restrict__ Bw,
                                               const float* __restrict__ bias,
                                               void* __restrict__ Cout,
                                               const float* __restrict__ res,
                                               int M, int N, int K) {
    __shared__ __align__(16) unsigned short As[2][128 * 32];
    __shared__ __align__(16) unsigned short Bs[2][128 * 32];
    const int t = threadIdx.x, l = t & 63, w = t >> 6;
    const int bm = (SWAPXY ? blockIdx.y : blockIdx.x) * 128;
    const int bn = (SWAPXY ? blockIdx.x : blockIdx.y) * 128;
    const int wr = w >> 1, wc = w & 1;
    f32x4 acc[4][4] = {};

    const int ra0 = t >> 2, ka0 = (t & 3) * 8;
    const int ra1 = (t + 256) >> 2, ka1 = ((t + 256) & 3) * 8;
    const unsigned short* Ar0 = A + (size_t)min(bm + ra0, M - 1) * K + ka0;
    const unsigned short* Ar1 = A + (size_t)min(bm + ra1, M - 1) * K + ka1;
    const unsigned short* Br0 = Bw + (size_t)(bn + ra0) * K + ka0;
    const unsigned short* Br1 = Bw + (size_t)(bn + ra1) * K + ka1;
    const int lo0 = (0 * 256 + w * 64) * 8, lo1 = (1 * 256 + w * 64) * 8;
    const int lr = l & 15, lk = (l >> 4) * 8;

    gload_lds16(Ar0, As[0] + lo0);
    gload_lds16(Ar1, As[0] + lo1);
    gload_lds16(Br0, Bs[0] + lo0);
    gload_lds16(Br1, Bs[0] + lo1);
    int cur = 0;
    for (int k0 = 0; k0 < K; k0 += 32) {
        if (k0 + 32 < K) {
            gload_lds16(Ar0 + k0 + 32, As[cur ^ 1] + lo0);
            gload_lds16(Ar1 + k0 + 32, As[cur ^ 1] + lo1);
            gload_lds16(Br0 + k0 + 32, Bs[cur ^ 1] + lo0);
            gload_lds16(Br1 + k0 + 32, Bs[cur ^ 1] + lo1);
            WAIT_VMCNT_4();
        } else {
            WAIT_VMCNT_0();
        }
        BARRIER_RAW();
        bf16x8 a[4], bfr[4];
#pragma unroll
        for (int m = 0; m < 4; m++)
            a[m] = *(const bf16x8*)(As[cur] + (wr * 64 + m * 16 + lr) * 32 + lk);
#pragma unroll
        for (int n = 0; n < 4; n++)
            bfr[n] = *(const bf16x8*)(Bs[cur] + (wc * 64 + n * 16 + lr) * 32 + lk);
#pragma unroll
        for (int m = 0; m < 4; m++)
#pragma unroll
            for (int n = 0; n < 4; n++)
                acc[m][n] = mfma16(a[m], bfr[n], acc[m][n]);
        BARRIER_RAW();
        cur ^= 1;
    }

#pragma unroll
    for (int m = 0; m < 4; m++) {
#pragma unroll
        for (int r = 0; r < 4; r++) {
            int gm = bm + wr * 64 + m * 16 + (l >> 4) * 4 + r;
            if (gm >= M) continue;
#pragma unroll
            for (int n = 0; n < 4; n++) {
                int gn = bn + wc * 64 + n * 16 + lr;
                float vb = acc[m][n][r] + bias[gn];
                if (MODE == 1) {
                    float gl = 0.5f * vb * (1.0f + erff(vb * 0.70710678118f));
                    ((unsigned short*)Cout)[(size_t)gm * N + gn] = f2bf(gl);
                } else {
                    ((float*)Cout)[(size_t)gm * N + gn] = vb + res[(size_t)gm * N + gn];
                }
            }
        }
    }
}

// ---------------- split-K NT GEMM: partials[z][m][n], K chunk = KFULL/SPLITK ----------------
__global__ __launch_bounds__(256) void gemm_splitk(const unsigned short* __restrict__ A,
                                                   const unsigned short* __restrict__ Bw,
                                                   float* __restrict__ parts,
                                                   int M, int N, int KFULL) {
    __shared__ __align__(16) unsigned short As[2][128 * 32];
    __shared__ __align__(16) unsigned short Bs[2][128 * 32];
    const int t = threadIdx.x, l = t & 63, w = t >> 6;
    const int bm = blockIdx.x * 128, bn = blockIdx.y * 128;
    const int KC = KFULL / SPLITK;
    const int kbeg = blockIdx.z * KC;
    const int wr = w >> 1, wc = w & 1;
    f32x4 acc[4][4] = {};

    const int ra0 = t >> 2, ka0 = (t & 3) * 8;
    const int ra1 = (t + 256) >> 2, ka1 = ((t + 256) & 3) * 8;
    const unsigned short* Ar0 = A + (size_t)min(bm + ra0, M - 1) * KFULL + kbeg + ka0;
    const unsigned short* Ar1 = A + (size_t)min(bm + ra1, M - 1) * KFULL + kbeg + ka1;
    const unsigned short* Br0 = Bw + (size_t)(bn + ra0) * KFULL + kbeg + ka0;
    const unsigned short* Br1 = Bw + (size_t)(bn + ra1) * KFULL + kbeg + ka1;
    const int lo0 = (0 * 256 + w * 64) * 8, lo1 = (1 * 256 + w * 64) * 8;
    const int lr = l & 15, lk = (l >> 4) * 8;

    gload_lds16(Ar0, As[0] + lo0);
    gload_lds16(Ar1, As[0] + lo1);
    gload_lds16(Br0, Bs[0] + lo0);
    gload_lds16(Br1, Bs[0] + lo1);
    int cur = 0;
    for (int k0 = 0; k0 < KC; k0 += 32) {
        if (k0 + 32 < KC) {
            gload_lds16(Ar0 + k0 + 32, As[cur ^ 1] + lo0);
            gload_lds16(Ar1 + k0 + 32, As[cur ^ 1] + lo1);
            gload_lds16(Br0 + k0 + 32, Bs[cur ^ 1] + lo0);
            gload_lds16(Br1 + k0 + 32, Bs[cur ^ 1] + lo1);
            WAIT_VMCNT_4();
        } else {
            WAIT_VMCNT_0();
        }
        BARRIER_RAW();
        bf16x8 a[4], bfr[4];
#pragma unroll
        for (int m = 0; m < 4; m++)
            a[m] = *(const bf16x8*)(As[cur] + (wr * 64 + m * 16 + lr) * 32 + lk);
#pragma unroll
        for (int n = 0; n < 4; n++)
            bfr[n] = *(const bf16x8*)(Bs[cur] + (wc * 64 + n * 16 + lr) * 32 + lk);
#pragma unroll
        for (int m = 0; m < 4; m++)
#pragma unroll
            for (int n = 0; n < 4; n++)
                acc[m][n] = mfma16(a[m], bfr[n], acc[m][n]);
        BARRIER_RAW();
        cur ^= 1;
    }

    float* po = parts + (size_t)blockIdx.z * M * N;
#pragma unroll
    for (int m = 0; m < 4; m++) {
#pragma unroll
        for (int r = 0; r < 4; r++) {
            int gm = bm + wr * 64 + m * 16 + (l >> 4) * 4 + r;
            if (gm >= M) continue;
#pragma unroll
            for (int n = 0; n < 4; n++) {
                int gn = bn + wc * 64 + n * 16 + lr;
                po[(size_t)gm * N + gn] = acc[m][n][r];
            }
        }
    }
}

// ---------------- classifier head (folds last-layer split-K partials + b2) ----------------
__global__ __launch_bounds__(256) void head_kernel(const float* __restrict__ x,
                                                   const float* __restrict__ Wh,
                                                   const float* __restrict__ bh,
                                                   float* __restrict__ logits,
                                                   const float* __restrict__ cparts,
                                                   const float* __restrict__ b2l) {
    __shared__ float xs[768];
    int b = blockIdx.x;
    int tid = threadIdx.x;
#pragma unroll
    for (int i = 0; i < 3; i++) {
        int c = tid + i * 256;
        float v = x[(size_t)b * SEQ * DIM + c];
        if (cparts) {
            v += b2l[c];
#pragma unroll
            for (int kc = 0; kc < SPLITK; kc++)
                v += cparts[((size_t)kc * NBATCH + b) * DIM + c];
        }
        xs[c] = v;
    }
    __syncthreads();
    int wave = tid >> 6, lane = tid & 63;
    int o = blockIdx.y * 4 + wave;
    if (o < NOUT) {
        float acc = 0;
#pragma unroll
        for (int t = 0; t < 12; t++) {
            int d = lane + t * 64;
            acc = fmaf(xs[d], Wh[(size_t)o * DIM + d], acc);
        }
#pragma unroll
        for (int off = 32; off > 0; off >>= 1) acc += __shfl_down(acc, off, 64);
        if (lane == 0) logits[b * NOUT + o] = acc + bh[o];
    }
}

__global__ __launch_bounds__(256) void softmax_kernel(const float* __restrict__ logits,
                                                      float* __restrict__ out) {
    __shared__ float tmp[4];
    int b = blockIdx.x, tid = threadIdx.x;
    float vals[4];
    float mx = -1e30f;
#pragma unroll
    for (int i = 0; i < 4; i++) {
        int c = tid + i * 256;
        vals[i] = (c < NOUT) ? logits[b * NOUT + c] : -1e30f;
        mx = fmaxf(mx, vals[i]);
    }
#pragma unroll
    for (int o = 32; o > 0; o >>= 1) mx = fmaxf(mx, __shfl_down(mx, o, 64));
    int wave = tid >> 6, lane = tid & 63;
    __syncthreads();
    if (lane == 0) tmp[wave] = mx;
    __syncthreads();
    mx = fmaxf(fmaxf(tmp[0], tmp[1]), fmaxf(tmp[2], tmp[3]));
    float s = 0;
#pragma unroll
    for (int i = 0; i < 4; i++) {
        int c = tid + i * 256;
        if (c < NOUT) {
            vals[i] = __expf(vals[i] - mx);
            s += vals[i];
        } else vals[i] = 0.f;
    }
#pragma unroll
    for (int o = 32; o > 0; o >>= 1) s += __shfl_down(s, o, 64);
    __syncthreads();
    if (lane == 0) tmp[wave] = s;
    __syncthreads();
    s = tmp[0] + tmp[1] + tmp[2] + tmp[3];
    float invs = 1.0f / s;
#pragma unroll
    for (int i = 0; i < 4; i++) {
        int c = tid + i * 256;
        if (c < NOUT) out[b * NOUT + c] = vals[i] * invs;
    }
}

extern "C" void kernel_launch(void* const* d_in, const int* in_sizes, int n_in,
                              void* d_out, int out_size, void* d_ws, size_t ws_size,
                              hipStream_t stream) {
    const float* images = (const float*)d_in[0];
    const float* Wp   = (const float*)d_in[1];
    const float* bp   = (const float*)d_in[2];
    const float* cls  = (const float*)d_in[3];
    const float* pos  = (const float*)d_in[4];
    const float* ln1g = (const float*)d_in[5];
    const float* ln1b = (const float*)d_in[6];
    const float* Wq   = (const float*)d_in[7];
    const float* bq   = (const float*)d_in[8];
    const float* Wk   = (const float*)d_in[9];
    const float* bk   = (const float*)d_in[10];
    const float* Wv   = (const float*)d_in[11];
    const float* bv   = (const float*)d_in[12];
    const float* ln2g = (const float*)d_in[13];
    const float* ln2b = (const float*)d_in[14];
    const float* W1   = (const float*)d_in[15];
    const float* b1   = (const float*)d_in[16];
    const float* W2   = (const float*)d_in[17];
    const float* b2   = (const float*)d_in[18];
    const float* Wh   = (const float*)d_in[19];
    const float* bh   = (const float*)d_in[20];
    float* out = (float*)d_out;

    const size_t NX = (size_t)MROWS * DIM;              // 4,841,472
    const size_t NIMG = (size_t)NBATCH * 3 * 224 * 224; // 4,816,896
    const size_t NW = (size_t)MDIM * DIM;               // 2,359,296 per layer

    char* p = (char*)d_ws;
    float* x      = (float*)p;            p += NX * 4;
    unsigned short* hb = (unsigned short*)p; p += NX * 2;   // attn out, bf16
    float* logits = (float*)p;            p += (size_t)NBATCH * NOUT * 4;
    unsigned short* hbf   = (unsigned short*)p; p += NX * 2;
    unsigned short* h2bf  = (unsigned short*)p; p += NX * 2;
    unsigned short* mid   = (unsigned short*)p; p += (size_t)MROWS * MDIM * 2;
    unsigned short* wqkvb = (unsigned short*)p; p += (size_t)NLAYER * NHEAD * 12288 * 2;
    unsigned short* imgbf = (unsigned short*)p; p += NIMG * 2;
    unsigned short* wpbf  = (unsigned short*)p; p += (size_t)DIM * DIM * 2;

    size_t used = (size_t)(p - (char*)d_ws);
    bool skq = ws_size >= used + (size_t)SPLITK * NX * 4;
    float* parts = (float*)p;
    if (skq) p += (size_t)SPLITK * NX * 4;
    used = (size_t)(p - (char*)d_ws);
    bool big = ws_size >= used + (size_t)2 * NLAYER * NW * 2;
    unsigned short* w1a = (unsigned short*)p;
    unsigned short* w2a = big ? w1a + (size_t)NLAYER * NW : w1a + NW;

    cls_pos_kernel<<<dim3(NBATCH), dim3(256), 0, stream>>>(cls, pos, x);
    cvt4<<<dim3(2048), dim3(256), 0, stream>>>(images, imgbf, (int)(NIMG / 4));
    cvt4<<<dim3(576), dim3(256), 0, stream>>>(Wp, wpbf, (int)(DIM * DIM / 4));
    cvt_qkvw<<<dim3(1024), dim3(256), 0, stream>>>(Wq, Wk, Wv, wqkvb);
    gemm_patch_bf<<<dim3(49, 6), dim3(256), 0, stream>>>(imgbf, wpbf, bp, pos, x);
    if (big) {
        cvt4<<<dim3(2048), dim3(256), 0, stream>>>(W1, w1a, (int)(NLAYER * NW / 4));
        cvt4<<<dim3(2048), dim3(256), 0, stream>>>(W2, w2a, (int)(NLAYER * NW / 4));
    }

    for (int l = 0; l < NLAYER; l++) {
        const unsigned short* wl1 = big ? w1a + (size_t)l * NW : w1a;
        const unsigned short* wl2 = big ? w2a + (size_t)l * NW : w2a;
        if (!big) {
            cvt4<<<dim3(2048), dim3(256), 0, stream>>>(W1 + (size_t)l * NW, w1a, (int)(NW / 4));
            cvt4<<<dim3(2048), dim3(256), 0, stream>>>(W2 + (size_t)l * NW, w1a + NW, (int)(NW / 4));
        }
        if (skq && l > 0) {
            ln_wave<0, 1><<<dim3(MROWS / 4), dim3(256), 0, stream>>>(
                x, nullptr, x, hbf, ln1g + l * DIM, ln1b + l * DIM, parts, b2 + (l - 1) * DIM, 1);
        } else {
            ln_wave<0, 0><<<dim3(MROWS / 4), dim3(256), 0, stream>>>(
                x, nullptr, nullptr, hbf, ln1g + l * DIM, ln1b + l * DIM, nullptr, nullptr, 1);
        }
        bool last = skq && (l == NLAYER - 1);
        if (last) {
            fused_attn<1><<<dim3(NBATCH, NHEAD), dim3(512), 0, stream>>>(
                hbf, wqkvb + (size_t)l * NHEAD * 12288,
                bq + l * NHEAD * DH, bk + l * NHEAD * DH, bv + l * NHEAD * DH, hb);
            ln_wave<1, 0><<<dim3(NBATCH / 4), dim3(256), 0, stream>>>(
                x, hb, x, h2bf, ln2g + l * DIM, ln2b + l * DIM, nullptr, nullptr, SEQ);
            gemm_bf<1, 1><<<dim3(24, 1), dim3(256), 0, stream>>>(
                h2bf, wl1, b1 + l * MDIM, mid, nullptr, NBATCH, MDIM, DIM);
            gemm_splitk<<<dim3(1, 6, SPLITK), dim3(256), 0, stream>>>(
                mid, wl2, parts, NBATCH, DIM, MDIM);
        } else {
            fused_attn<13><<<dim3(NBATCH, NHEAD), dim3(512), 0, stream>>>(
                hbf, wqkvb + (size_t)l * NHEAD * 12288,
                bq + l * NHEAD * DH, bk + l * NHEAD * DH, bv + l * NHEAD * DH, hb);
            ln_wave<1, 0><<<dim3(MROWS / 4), dim3(256), 0, stream>>>(
                x, hb, x, h2bf, ln2g + l * DIM, ln2b + l * DIM, nullptr, nullptr, 1);
            gemm_bf<1, 1><<<dim3(24, 50), dim3(256), 0, stream>>>(
                h2bf, wl1, b1 + l * MDIM, mid, nullptr, MROWS, MDIM, DIM);
            if (skq) {
                gemm_splitk<<<dim3(50, 6, SPLITK), dim3(256), 0, stream>>>(
                    mid, wl2, parts, MROWS, DIM, MDIM);
            } else {
                gemm_bf<2, 0><<<dim3(50, 6), dim3(256), 0, stream>>>(
                    mid, wl2, b2 + l * DIM, x, x, MROWS, DIM, MDIM);
            }
        }
    }

    head_kernel<<<dim3(NBATCH, 250), dim3(256), 0, stream>>>(
        x, Wh, bh, logits,
        skq ? parts : nullptr, skq ? b2 + (NLAYER - 1) * DIM : nullptr);
    softmax_kernel<<<dim3(NBATCH), dim3(256), 0, stream>>>(logits, out);
}